// Round 7
// baseline (726.842 us; speedup 1.0000x reference)
//
#include <hip/hip_runtime.h>
#include <math.h>

typedef unsigned short ushort_t;
typedef __attribute__((ext_vector_type(8))) short bf16x8;
typedef __attribute__((ext_vector_type(4))) float f32x4;

__device__ __forceinline__ float bf2f(unsigned short u) {
    union { unsigned int i; float f; } x; x.i = ((unsigned int)u) << 16; return x.f;
}
__device__ __forceinline__ unsigned short f2bf(float f) {
    union { float f; unsigned int i; } x; x.f = f;          // round-to-nearest-even
    unsigned int lsb = (x.i >> 16) & 1u;
    return (unsigned short)((x.i + 0x7fffu + lsb) >> 16);
}

// ---------------- edge_index dtype hedge ----------------

__global__ __launch_bounds__(1024) void detect_i64(const int* __restrict__ ei,
                                                   int nwords, int* __restrict__ flag) {
    __shared__ int s_any;
    if (threadIdx.x == 0) s_any = 0;
    __syncthreads();
    int any = 0;
    for (int i = threadIdx.x; 2 * i + 1 < nwords; i += 1024)
        if (ei[2 * i + 1] != 0) any = 1;
    if (any) s_any = 1;           // race-benign
    __syncthreads();
    if (threadIdx.x == 0) flag[0] = (s_any == 0) ? 1 : 0;   // 1 => int64 layout
}

// normalize indices AND count degrees (fused; deg must be pre-zeroed)
__global__ __launch_bounds__(256) void normalize_count(const int* __restrict__ ei, int E,
                                                       const int* __restrict__ flag,
                                                       int* __restrict__ s_out,
                                                       int* __restrict__ d_out,
                                                       int* __restrict__ deg) {
    int e = blockIdx.x * 256 + threadIdx.x;
    if (e >= E) return;
    int s, d;
    if (flag[0]) {                // int64: element i at int32 word 2i (little-endian)
        s = ei[2 * e];
        d = ei[2 * (E + e)];
    } else {                      // int32 flat [2][E]
        s = ei[e];
        d = ei[E + e];
    }
    s_out[e] = s;
    d_out[e] = d;
    atomicAdd(&deg[d], 1);
}

// ---------------- CSR build ----------------

__global__ __launch_bounds__(256) void zero_i32(int* __restrict__ p, int n) {
    int i = blockIdx.x * 256 + threadIdx.x;
    if (i < n) p[i] = 0;
}

// single-block exclusive scan over deg -> offs, cursor; also dinv = rsqrt(deg+1)
__global__ __launch_bounds__(1024) void scan_kernel(const int* __restrict__ deg,
                                                    int* __restrict__ offs,
                                                    int* __restrict__ cursor,
                                                    float* __restrict__ dinv, int n) {
    __shared__ int wsum[16];
    __shared__ int s_carry;
    int tid = threadIdx.x, lane = tid & 63, wid = tid >> 6;
    if (tid == 0) s_carry = 0;
    __syncthreads();
    for (int base = 0; base < n; base += 1024) {
        int i = base + tid;
        int v = (i < n) ? deg[i] : 0;
        int x = v;
        #pragma unroll
        for (int d = 1; d < 64; d <<= 1) {
            int y = __shfl_up(x, d, 64);
            if (lane >= d) x += y;
        }
        if (lane == 63) wsum[wid] = x;
        __syncthreads();
        int carry = s_carry;
        __syncthreads();           // everyone read carry before thread0 rewrites
        if (tid == 0) {
            int run = 0;
            #pragma unroll
            for (int w = 0; w < 16; ++w) { int t = wsum[w]; wsum[w] = run; run += t; }
            s_carry = carry + run;
        }
        __syncthreads();
        if (i < n) {
            int excl = carry + wsum[wid] + (x - v);
            offs[i] = excl;
            cursor[i] = excl;
            dinv[i] = rsqrtf((float)(v + 1));   // +1 self loop
        }
        __syncthreads();           // protect wsum before next iteration
    }
    if (tid == 0) offs[n] = s_carry;
}

// fill CSR: ONE packed 8B scatter per edge (src, eid)
__global__ __launch_bounds__(256) void fill_csr(const int* __restrict__ src,
                                                const int* __restrict__ dst,
                                                int* __restrict__ cursor,
                                                int2* __restrict__ csr_se, int E) {
    int e = blockIdx.x * 256 + threadIdx.x;
    if (e < E) {
        int pos = atomicAdd(&cursor[dst[e]], 1);
        csr_se[pos] = make_int2(src[e], e);
    }
}

// csr_dst by segment: sequential (coalesced) writes, no scatter
__global__ __launch_bounds__(256) void fill_seg(const int* __restrict__ offs,
                                                int* __restrict__ csr_dst, int n_nodes) {
    int wid = threadIdx.x >> 6, lane = threadIdx.x & 63;
    int node = blockIdx.x * 4 + wid;
    if (node >= n_nodes) return;
    int beg = offs[node], end = offs[node + 1];
    for (int i = beg + lane; i < end; i += 64) csr_dst[i] = node;
}

// ---------------- bf16 MFMA GEMM ----------------
// out[m][n] = scale_m * (sum_k A[m][k] W[k][n]) + bias_n
// A: [M][K] f32, W: [K][128] f32; staged to LDS as bf16. BM=64 (4 waves x 16 rows),
// BN=128 (8 frags), BK=32. mfma_f32_16x16x32_bf16; K-slot permutation is consistent
// between A and B stages so any HW k-order cancels; C/D map: col=lane&15,
// row=(lane>>4)*4+reg (HW-verified m89/m91).

#define APAD 40   // bf16 elems per LDS row (32 used; 80B stride keeps 16B alignment)
#define BPAD 40

__global__ __launch_bounds__(256) void gemm_mfma(const float* __restrict__ A,
                                                 const float* __restrict__ W,
                                                 void* __restrict__ outv,
                                                 const float* __restrict__ dinv,
                                                 const float* __restrict__ bias,
                                                 int M, int K, int out_bf16) {
    __shared__ __attribute__((aligned(16))) ushort_t As[64 * APAD];  // [row][k]
    __shared__ __attribute__((aligned(16))) ushort_t Bt[128 * BPAD]; // [col][k]
    int tid = threadIdx.x;
    int wave = tid >> 6, lane = tid & 63;
    int l15 = lane & 15, lg = lane >> 4;
    int block_m = blockIdx.x * 64;
    f32x4 acc[8];
    #pragma unroll
    for (int i = 0; i < 8; ++i) acc[i] = (f32x4){0.f, 0.f, 0.f, 0.f};

    for (int k0 = 0; k0 < K; k0 += 32) {
        // stage A: 64 rows x 32 k (2 reps x [32 rows x 8 thr x float4])
        #pragma unroll
        for (int rep = 0; rep < 2; ++rep) {
            int r = rep * 32 + (tid >> 3);
            int kc = (tid & 7) * 4;
            int gr = block_m + r;
            int grc = gr < M ? gr : M - 1;
            float4 v = *(const float4*)(&A[(size_t)grc * K + k0 + kc]);
            if (gr >= M) v = make_float4(0.f, 0.f, 0.f, 0.f);
            ushort_t* p = &As[r * APAD + kc];
            p[0] = f2bf(v.x); p[1] = f2bf(v.y); p[2] = f2bf(v.z); p[3] = f2bf(v.w);
        }
        // stage W^T: 32 k x 128 n -> Bt[n][k] (4 reps x float4, coalesced)
        #pragma unroll
        for (int rep = 0; rep < 4; ++rep) {
            int l4 = rep * 256 + tid;          // float4 index 0..1023
            int kr = l4 >> 5;                  // 0..31
            int n4 = (l4 & 31) * 4;            // 0..124
            float4 v = *(const float4*)(&W[(size_t)(k0 + kr) * 128 + n4]);
            Bt[(n4 + 0) * BPAD + kr] = f2bf(v.x);
            Bt[(n4 + 1) * BPAD + kr] = f2bf(v.y);
            Bt[(n4 + 2) * BPAD + kr] = f2bf(v.z);
            Bt[(n4 + 3) * BPAD + kr] = f2bf(v.w);
        }
        __syncthreads();
        bf16x8 af = *(const bf16x8*)(&As[(wave * 16 + l15) * APAD + lg * 8]);
        #pragma unroll
        for (int nf = 0; nf < 8; ++nf) {
            bf16x8 bf = *(const bf16x8*)(&Bt[(nf * 16 + l15) * BPAD + lg * 8]);
            acc[nf] = __builtin_amdgcn_mfma_f32_16x16x32_bf16(af, bf, acc[nf], 0, 0, 0);
        }
        __syncthreads();
    }
    int orow = block_m + wave * 16 + lg * 4;
    #pragma unroll
    for (int nf = 0; nf < 8; ++nf) {
        int col = nf * 16 + l15;
        float bb = bias ? bias[col] : 0.f;
        #pragma unroll
        for (int j = 0; j < 4; ++j) {
            int m = orow + j;
            if (m < M) {
                float s = dinv ? dinv[m] : 1.f;
                float o = acc[nf][j] * s + bb;
                if (out_bf16)
                    ((ushort_t*)outv)[(size_t)m * 128 + col] = f2bf(o);
                else
                    ((float*)outv)[(size_t)m * 128 + col] = o;
            }
        }
    }
}

// ---------------- pull aggregation (bf16 gather table, f32 accum) ----------------
// out[n] = act( dinv[n]*(g[n] + sum_{i in CSR[n]} g[src_i]) + bias )

__global__ __launch_bounds__(256) void pull_agg(const ushort_t* __restrict__ g,
                                                const int2* __restrict__ csr_se,
                                                const int* __restrict__ offs,
                                                const float* __restrict__ dinv,
                                                const float* __restrict__ bias,
                                                float* __restrict__ out,
                                                int n_nodes, int do_relu) {
    int wid = threadIdx.x >> 6;
    int lane = threadIdx.x & 63;
    int node = blockIdx.x * 4 + wid;
    if (node >= n_nodes) return;
    int beg = offs[node], end = offs[node + 1];
    ushort2 sv = *(const ushort2*)(g + (size_t)node * 128 + 2 * lane);
    float a0 = bf2f(sv.x), a1 = bf2f(sv.y);          // self-loop term
    int i = beg;
    for (; i + 4 <= end; i += 4) {
        int s0 = csr_se[i].x, s1 = csr_se[i + 1].x;
        int s2 = csr_se[i + 2].x, s3 = csr_se[i + 3].x;
        ushort2 v0 = *(const ushort2*)(g + (size_t)s0 * 128 + 2 * lane);
        ushort2 v1 = *(const ushort2*)(g + (size_t)s1 * 128 + 2 * lane);
        ushort2 v2 = *(const ushort2*)(g + (size_t)s2 * 128 + 2 * lane);
        ushort2 v3 = *(const ushort2*)(g + (size_t)s3 * 128 + 2 * lane);
        a0 += bf2f(v0.x) + bf2f(v1.x) + bf2f(v2.x) + bf2f(v3.x);
        a1 += bf2f(v0.y) + bf2f(v1.y) + bf2f(v2.y) + bf2f(v3.y);
    }
    for (; i < end; ++i) {
        ushort2 v = *(const ushort2*)(g + (size_t)csr_se[i].x * 128 + 2 * lane);
        a0 += bf2f(v.x); a1 += bf2f(v.y);
    }
    float s = dinv[node];
    float v0 = a0 * s + bias[2 * lane];
    float v1 = a1 * s + bias[2 * lane + 1];
    if (do_relu) { v0 = fmaxf(v0, 0.f); v1 = fmaxf(v1, 0.f); }
    *(float2*)(&out[(size_t)node * 128 + 2 * lane]) = make_float2(v0, v1);
}

// ---------------- factorized edge scorer (CSR order, bf16 u/v tables) ----------
// score[eid] = sigmoid( sum_j relu(u[s][j] + v[d][j]) * W4[j] + b4 )

__global__ __launch_bounds__(256) void edge_score_csr(const ushort_t* __restrict__ u,
                                                      const ushort_t* __restrict__ v,
                                                      const int2* __restrict__ csr_se,
                                                      const int* __restrict__ csr_dst,
                                                      const float* __restrict__ W4,
                                                      const float* __restrict__ b4,
                                                      float* __restrict__ out, int E) {
    __shared__ int2 s_se[32];
    __shared__ int s_dst[32];
    int tid = threadIdx.x;
    long base = (long)blockIdx.x * 32;
    if (tid < 32) {
        long p = base + tid;
        s_se[tid] = (p < E) ? csr_se[p] : make_int2(0, 0);
    } else if (tid < 64) {
        long p = base + (tid - 32);
        s_dst[tid - 32] = (p < E) ? csr_dst[p] : 0;
    }
    __syncthreads();
    int grp = tid >> 5;          // 0..7
    int lane = tid & 31;
    float4 w4 = *(const float4*)(&W4[lane * 4]);
    float b4v = b4[0];
    #pragma unroll
    for (int i = 0; i < 4; ++i) {
        int ei = grp * 4 + i;    // 0..31
        int s = s_se[ei].x, d = s_dst[ei];
        ushort4 a = *(const ushort4*)(u + (size_t)s * 128 + lane * 4);
        ushort4 b = *(const ushort4*)(v + (size_t)d * 128 + lane * 4);
        float p = fmaxf(bf2f(a.x) + bf2f(b.x), 0.f) * w4.x
                + fmaxf(bf2f(a.y) + bf2f(b.y), 0.f) * w4.y
                + fmaxf(bf2f(a.z) + bf2f(b.z), 0.f) * w4.z
                + fmaxf(bf2f(a.w) + bf2f(b.w), 0.f) * w4.w;
        #pragma unroll
        for (int m = 16; m >= 1; m >>= 1) p += __shfl_xor(p, m, 64);
        if (lane == 0 && base + ei < E)
            out[s_se[ei].y] = 1.f / (1.f + expf(-(p + b4v)));
    }
}

// ---------------- launcher ----------------

extern "C" void kernel_launch(void* const* d_in, const int* in_sizes, int n_in,
                              void* d_out, int out_size, void* d_ws, size_t ws_size,
                              hipStream_t stream) {
    const float* x  = (const float*)d_in[0];
    const int*   ei = (const int*)d_in[1];
    const float* W1 = (const float*)d_in[2];
    const float* b1 = (const float*)d_in[3];
    const float* W2 = (const float*)d_in[4];
    const float* b2 = (const float*)d_in[5];
    const float* W3 = (const float*)d_in[6];
    const float* b3 = (const float*)d_in[7];
    const float* W4 = (const float*)d_in[8];
    const float* b4 = (const float*)d_in[9];

    int N = in_sizes[0] / 256;      // 50000
    int E = in_sizes[1] / 2;        // 1.6M

    char* ws = (char*)d_ws;
    size_t off = 0;
    auto alloc = [&](size_t bytes) -> void* {
        void* p = ws + off;
        off += (bytes + 255) & ~(size_t)255;
        return p;
    };
    int*      flag    = (int*)     alloc(256);
    int*      srcn    = (int*)     alloc((size_t)E * 4);
    int*      dstn    = (int*)     alloc((size_t)E * 4);
    int*      deg     = (int*)     alloc((size_t)N * 4);
    int*      offs    = (int*)     alloc((size_t)(N + 1) * 4);
    int*      cursor  = (int*)     alloc((size_t)N * 4);
    float*    dinv    = (float*)   alloc((size_t)N * 4);
    int2*     csr_se  = (int2*)    alloc((size_t)E * 8);
    int*      csr_dst = (int*)     alloc((size_t)E * 4);
    ushort_t* gbuf    = (ushort_t*)alloc((size_t)N * 128 * 2);   // bf16 gather table
    ushort_t* ubuf    = (ushort_t*)alloc((size_t)N * 128 * 2);   // bf16 u table
    ushort_t* vbuf    = (ushort_t*)alloc((size_t)N * 128 * 2);   // bf16 v table
    float*    hbuf    = (float*)   alloc((size_t)N * 128 * 4);   // f32 h (GEMM input)
    (void)ws_size; (void)n_in; (void)out_size;

    float* outp = (float*)d_out;
    int gE = (E + 255) / 256;
    int gN4 = (N + 3) / 4;

    // dtype hedge + fused normalize/degree-count
    int nwords = (2 * E < 4096) ? 2 * E : 4096;
    detect_i64<<<1, 1024, 0, stream>>>(ei, nwords, flag);
    zero_i32<<<(N + 255) / 256, 256, 0, stream>>>(deg, N);
    normalize_count<<<gE, 256, 0, stream>>>(ei, E, flag, srcn, dstn, deg);
    scan_kernel<<<1, 1024, 0, stream>>>(deg, offs, cursor, dinv, N);
    fill_csr<<<gE, 256, 0, stream>>>(srcn, dstn, cursor, csr_se, E);
    fill_seg<<<gN4, 256, 0, stream>>>(offs, csr_dst, N);

    int gM = (N + 63) / 64;
    // layer 1: g1 = bf16(dinv * (x @ W1));  h1 = relu(dinv*(sum g1) + b1)  [f32]
    gemm_mfma<<<gM, 256, 0, stream>>>(x, W1, gbuf, dinv, nullptr, N, 256, 1);
    pull_agg<<<gN4, 256, 0, stream>>>(gbuf, csr_se, offs, dinv, b1, hbuf, N, 1);
    // layer 2: g2 = bf16(dinv * (h1 @ W2)); h2 = dinv*(sum g2) + b2        [f32]
    gemm_mfma<<<gM, 256, 0, stream>>>(hbuf, W2, gbuf, dinv, nullptr, N, 128, 1);
    pull_agg<<<gN4, 256, 0, stream>>>(gbuf, csr_se, offs, dinv, b2, hbuf, N, 0);
    // factorized edge MLP: u = bf16(h2 @ W3a), v = bf16(h2 @ W3b + b3)
    gemm_mfma<<<gM, 256, 0, stream>>>(hbuf, W3, ubuf, nullptr, nullptr, N, 128, 1);
    gemm_mfma<<<gM, 256, 0, stream>>>(hbuf, W3 + 128 * 128, vbuf, nullptr, b3, N, 128, 1);
    // score per edge, CSR order (v-row locality), scatter to original edge id
    edge_score_csr<<<(E + 31) / 32, 256, 0, stream>>>(ubuf, vbuf, csr_se, csr_dst,
                                                      W4, b4, outp, E);
}

// Round 8
// 634.284 us; speedup vs baseline: 1.1459x; 1.1459x over previous
//
#include <hip/hip_runtime.h>
#include <math.h>

typedef unsigned short ushort_t;
typedef __attribute__((ext_vector_type(8))) short bf16x8;
typedef __attribute__((ext_vector_type(4))) float f32x4;

__device__ __forceinline__ float bf2f(unsigned short u) {
    union { unsigned int i; float f; } x; x.i = ((unsigned int)u) << 16; return x.f;
}
__device__ __forceinline__ unsigned short f2bf(float f) {
    union { float f; unsigned int i; } x; x.f = f;          // round-to-nearest-even
    unsigned int lsb = (x.i >> 16) & 1u;
    return (unsigned short)((x.i + 0x7fffu + lsb) >> 16);
}

// ---------------- edge_index dtype hedge ----------------

__global__ __launch_bounds__(1024) void detect_i64(const int* __restrict__ ei,
                                                   int nwords, int* __restrict__ flag) {
    __shared__ int s_any;
    if (threadIdx.x == 0) s_any = 0;
    __syncthreads();
    int any = 0;
    for (int i = threadIdx.x; 2 * i + 1 < nwords; i += 1024)
        if (ei[2 * i + 1] != 0) any = 1;
    if (any) s_any = 1;           // race-benign
    __syncthreads();
    if (threadIdx.x == 0) flag[0] = (s_any == 0) ? 1 : 0;   // 1 => int64 layout
}

__global__ __launch_bounds__(256) void normalize_idx(const int* __restrict__ ei, int E,
                                                     const int* __restrict__ flag,
                                                     int* __restrict__ s_out,
                                                     int* __restrict__ d_out) {
    int e = blockIdx.x * 256 + threadIdx.x;
    if (e >= E) return;
    if (flag[0]) {                // int64: element i at int32 word 2i (little-endian)
        s_out[e] = ei[2 * e];
        d_out[e] = ei[2 * (E + e)];
    } else {                      // int32 flat [2][E]
        s_out[e] = ei[e];
        d_out[e] = ei[E + e];
    }
}

// ---------------- CSR build (XCD dst-range partitioned) ----------------
// blockIdx & 7 -> XCD under the %8 round-robin dispatch heuristic. Each XCD
// owns dst range [xcd*RB, xcd*RB+RB): its cursor/deg/csr lines stay in its
// private L2 (no cross-XCD dirty-line multiplication). Perf-only assumption.

__global__ __launch_bounds__(256) void zero_i32(int* __restrict__ p, int n) {
    int i = blockIdx.x * 256 + threadIdx.x;
    if (i < n) p[i] = 0;
}

__global__ __launch_bounds__(256) void count_deg_part(const int* __restrict__ dst,
                                                      int* __restrict__ deg,
                                                      int E, int RB) {
    int xcd = blockIdx.x & 7;
    int e = (blockIdx.x >> 3) * 256 + threadIdx.x;
    if (e >= E) return;
    int d = dst[e];
    if ((unsigned)(d - xcd * RB) < (unsigned)RB) atomicAdd(&deg[d], 1);
}

// single-block exclusive scan over deg -> offs, cursor; also dinv = rsqrt(deg+1)
__global__ __launch_bounds__(1024) void scan_kernel(const int* __restrict__ deg,
                                                    int* __restrict__ offs,
                                                    int* __restrict__ cursor,
                                                    float* __restrict__ dinv, int n) {
    __shared__ int wsum[16];
    __shared__ int s_carry;
    int tid = threadIdx.x, lane = tid & 63, wid = tid >> 6;
    if (tid == 0) s_carry = 0;
    __syncthreads();
    for (int base = 0; base < n; base += 1024) {
        int i = base + tid;
        int v = (i < n) ? deg[i] : 0;
        int x = v;
        #pragma unroll
        for (int d = 1; d < 64; d <<= 1) {
            int y = __shfl_up(x, d, 64);
            if (lane >= d) x += y;
        }
        if (lane == 63) wsum[wid] = x;
        __syncthreads();
        int carry = s_carry;
        __syncthreads();           // everyone read carry before thread0 rewrites
        if (tid == 0) {
            int run = 0;
            #pragma unroll
            for (int w = 0; w < 16; ++w) { int t = wsum[w]; wsum[w] = run; run += t; }
            s_carry = carry + run;
        }
        __syncthreads();
        if (i < n) {
            int excl = carry + wsum[wid] + (x - v);
            offs[i] = excl;
            cursor[i] = excl;
            dinv[i] = rsqrtf((float)(v + 1));   // +1 self loop
        }
        __syncthreads();           // protect wsum before next iteration
    }
    if (tid == 0) offs[n] = s_carry;
}

__global__ __launch_bounds__(256) void fill_csr_part(const int* __restrict__ src,
                                                     const int* __restrict__ dst,
                                                     int* __restrict__ cursor,
                                                     int2* __restrict__ csr_se,
                                                     int E, int RB) {
    int xcd = blockIdx.x & 7;
    int e = (blockIdx.x >> 3) * 256 + threadIdx.x;
    if (e >= E) return;
    int d = dst[e];
    if ((unsigned)(d - xcd * RB) < (unsigned)RB) {
        int pos = atomicAdd(&cursor[d], 1);
        csr_se[pos] = make_int2(src[e], e);
    }
}

// csr_dst by segment: sequential (coalesced) writes, no scatter
__global__ __launch_bounds__(256) void fill_seg(const int* __restrict__ offs,
                                                int* __restrict__ csr_dst, int n_nodes) {
    int wid = threadIdx.x >> 6, lane = threadIdx.x & 63;
    int node = blockIdx.x * 4 + wid;
    if (node >= n_nodes) return;
    int beg = offs[node], end = offs[node + 1];
    for (int i = beg + lane; i < end; i += 64) csr_dst[i] = node;
}

// ---------------- weight pre-convert: f32 [K][128] -> bf16 transposed [128][K] ----

__global__ __launch_bounds__(256) void conv_weights(const float* __restrict__ W1,
                                                    const float* __restrict__ W2,
                                                    const float* __restrict__ W3,
                                                    ushort_t* __restrict__ Wt1,
                                                    ushort_t* __restrict__ Wt2,
                                                    ushort_t* __restrict__ Wt3a,
                                                    ushort_t* __restrict__ Wt3b) {
    int t = blockIdx.x * 256 + threadIdx.x;
    if (t < 32768) {                 // W1 [256][128] -> Wt1 [128][256]
        int k = t >> 7, n = t & 127;
        Wt1[n * 256 + k] = f2bf(W1[t]);
    } else if (t < 49152) {          // W2 [128][128]
        int u = t - 32768; int k = u >> 7, n = u & 127;
        Wt2[n * 128 + k] = f2bf(W2[u]);
    } else if (t < 65536) {          // W3a = W3[0:128][:]
        int u = t - 49152; int k = u >> 7, n = u & 127;
        Wt3a[n * 128 + k] = f2bf(W3[u]);
    } else if (t < 81920) {          // W3b = W3[128:256][:]
        int u = t - 65536; int k = u >> 7, n = u & 127;
        Wt3b[n * 128 + k] = f2bf(W3[128 * 128 + u]);
    }
}

// ---------------- bf16 MFMA GEMM (half-K-resident B, packed staging) ----------
// out[m][n] = scale_m * (sum_k A[m][k] W[k][n]) + bias_n
// A: [M][K] f32 (converted to bf16 in LDS); Wt: [128][K] bf16 (pre-transposed).
// BM=64 (4 waves x 16 rows), BN=128 (8 frags), inner BK=32, B kept resident in
// 128-k halves. Fragment mapping identical to the round-5/7 verified kernel:
// A-frag As[row=lane&15][k=(lane>>4)*8+i], B-frag Bt[col=lane&15][same k],
// C/D col=lane&15, row=(lane>>4)*4+reg (HW-verified m89/m91).

#define ASTR 40    // ushorts per As row (80B: 2-way bank alias on b128 reads = free)
#define BSTR 136   // ushorts per Bt row (272B: 2-way alias = free)

__global__ __launch_bounds__(256) void gemm_mfma(const float* __restrict__ A,
                                                 const ushort_t* __restrict__ Wt,
                                                 void* __restrict__ outv,
                                                 const float* __restrict__ dinv,
                                                 const float* __restrict__ bias,
                                                 int M, int K, int out_bf16) {
    __shared__ __attribute__((aligned(16))) ushort_t Bt[128 * BSTR]; // [col][k-kh]
    __shared__ __attribute__((aligned(16))) ushort_t As[64 * ASTR];  // [row][k-k0]
    int tid = threadIdx.x;
    int wave = tid >> 6, lane = tid & 63;
    int l15 = lane & 15, lg = lane >> 4;
    int block_m = blockIdx.x * 64;
    f32x4 acc[8];
    #pragma unroll
    for (int i = 0; i < 8; ++i) acc[i] = (f32x4){0.f, 0.f, 0.f, 0.f};

    for (int kh = 0; kh < K; kh += 128) {
        // stage B half: 128 cols x 128 k, pure ushort4 copy (16 per thread)
        #pragma unroll
        for (int i = 0; i < 16; ++i) {
            int u = i * 256 + tid;             // ushort4 unit
            int col = u >> 5;                  // 32 quads per col
            int kq = (u & 31) * 4;
            ushort4 w = *(const ushort4*)(&Wt[(size_t)col * K + kh + kq]);
            *(ushort4*)(&Bt[col * BSTR + kq]) = w;
        }
        for (int k0 = kh; k0 < kh + 128; k0 += 32) {
            // stage A: 64 rows x 32 k, packed ushort4 stores (2 per thread)
            #pragma unroll
            for (int rep = 0; rep < 2; ++rep) {
                int unit = rep * 256 + tid;
                int r = unit >> 3;             // 0..63
                int kc = (unit & 7) * 4;       // 0..28
                int gr = block_m + r;
                int grc = gr < M ? gr : M - 1;
                float4 v = *(const float4*)(&A[(size_t)grc * K + k0 + kc]);
                if (gr >= M) v = make_float4(0.f, 0.f, 0.f, 0.f);
                ushort4 p;
                p.x = f2bf(v.x); p.y = f2bf(v.y); p.z = f2bf(v.z); p.w = f2bf(v.w);
                *(ushort4*)(&As[r * ASTR + kc]) = p;
            }
            __syncthreads();
            bf16x8 af = *(const bf16x8*)(&As[(wave * 16 + l15) * ASTR + lg * 8]);
            #pragma unroll
            for (int nf = 0; nf < 8; ++nf) {
                bf16x8 bf = *(const bf16x8*)(&Bt[(nf * 16 + l15) * BSTR +
                                                 (k0 - kh) + lg * 8]);
                acc[nf] = __builtin_amdgcn_mfma_f32_16x16x32_bf16(af, bf, acc[nf],
                                                                  0, 0, 0);
            }
            __syncthreads();
        }
    }
    int orow = block_m + wave * 16 + lg * 4;
    #pragma unroll
    for (int nf = 0; nf < 8; ++nf) {
        int col = nf * 16 + l15;
        float bb = bias ? bias[col] : 0.f;
        #pragma unroll
        for (int j = 0; j < 4; ++j) {
            int m = orow + j;
            if (m < M) {
                float s = dinv ? dinv[m] : 1.f;
                float o = acc[nf][j] * s + bb;
                if (out_bf16)
                    ((ushort_t*)outv)[(size_t)m * 128 + col] = f2bf(o);
                else
                    ((float*)outv)[(size_t)m * 128 + col] = o;
            }
        }
    }
}

// ---------------- pull aggregation (bf16 gather table, f32 accum) ----------------
// out[n] = act( dinv[n]*(g[n] + sum_{i in CSR[n]} g[src_i]) + bias )

__global__ __launch_bounds__(256) void pull_agg(const ushort_t* __restrict__ g,
                                                const int2* __restrict__ csr_se,
                                                const int* __restrict__ offs,
                                                const float* __restrict__ dinv,
                                                const float* __restrict__ bias,
                                                float* __restrict__ out,
                                                int n_nodes, int do_relu) {
    int wid = threadIdx.x >> 6;
    int lane = threadIdx.x & 63;
    int node = blockIdx.x * 4 + wid;
    if (node >= n_nodes) return;
    int beg = offs[node], end = offs[node + 1];
    ushort2 sv = *(const ushort2*)(g + (size_t)node * 128 + 2 * lane);
    float a0 = bf2f(sv.x), a1 = bf2f(sv.y);          // self-loop term
    int i = beg;
    for (; i + 4 <= end; i += 4) {
        int s0 = csr_se[i].x, s1 = csr_se[i + 1].x;
        int s2 = csr_se[i + 2].x, s3 = csr_se[i + 3].x;
        ushort2 v0 = *(const ushort2*)(g + (size_t)s0 * 128 + 2 * lane);
        ushort2 v1 = *(const ushort2*)(g + (size_t)s1 * 128 + 2 * lane);
        ushort2 v2 = *(const ushort2*)(g + (size_t)s2 * 128 + 2 * lane);
        ushort2 v3 = *(const ushort2*)(g + (size_t)s3 * 128 + 2 * lane);
        a0 += bf2f(v0.x) + bf2f(v1.x) + bf2f(v2.x) + bf2f(v3.x);
        a1 += bf2f(v0.y) + bf2f(v1.y) + bf2f(v2.y) + bf2f(v3.y);
    }
    for (; i < end; ++i) {
        ushort2 v = *(const ushort2*)(g + (size_t)csr_se[i].x * 128 + 2 * lane);
        a0 += bf2f(v.x); a1 += bf2f(v.y);
    }
    float s = dinv[node];
    float v0 = a0 * s + bias[2 * lane];
    float v1 = a1 * s + bias[2 * lane + 1];
    if (do_relu) { v0 = fmaxf(v0, 0.f); v1 = fmaxf(v1, 0.f); }
    *(float2*)(&out[(size_t)node * 128 + 2 * lane]) = make_float2(v0, v1);
}

// ---------------- factorized edge scorer (CSR order, bf16 u/v tables) ----------
// score[eid] = sigmoid( sum_j relu(u[s][j] + v[d][j]) * W4[j] + b4 )

__global__ __launch_bounds__(256) void edge_score_csr(const ushort_t* __restrict__ u,
                                                      const ushort_t* __restrict__ v,
                                                      const int2* __restrict__ csr_se,
                                                      const int* __restrict__ csr_dst,
                                                      const float* __restrict__ W4,
                                                      const float* __restrict__ b4,
                                                      float* __restrict__ out, int E) {
    __shared__ int2 s_se[32];
    __shared__ int s_dst[32];
    int tid = threadIdx.x;
    long base = (long)blockIdx.x * 32;
    if (tid < 32) {
        long p = base + tid;
        s_se[tid] = (p < E) ? csr_se[p] : make_int2(0, 0);
    } else if (tid < 64) {
        long p = base + (tid - 32);
        s_dst[tid - 32] = (p < E) ? csr_dst[p] : 0;
    }
    __syncthreads();
    int grp = tid >> 5;          // 0..7
    int lane = tid & 31;
    float4 w4 = *(const float4*)(&W4[lane * 4]);
    float b4v = b4[0];
    #pragma unroll
    for (int i = 0; i < 4; ++i) {
        int ei = grp * 4 + i;    // 0..31
        int s = s_se[ei].x, d = s_dst[ei];
        ushort4 a = *(const ushort4*)(u + (size_t)s * 128 + lane * 4);
        ushort4 b = *(const ushort4*)(v + (size_t)d * 128 + lane * 4);
        float p = fmaxf(bf2f(a.x) + bf2f(b.x), 0.f) * w4.x
                + fmaxf(bf2f(a.y) + bf2f(b.y), 0.f) * w4.y
                + fmaxf(bf2f(a.z) + bf2f(b.z), 0.f) * w4.z
                + fmaxf(bf2f(a.w) + bf2f(b.w), 0.f) * w4.w;
        #pragma unroll
        for (int m = 16; m >= 1; m >>= 1) p += __shfl_xor(p, m, 64);
        if (lane == 0 && base + ei < E)
            out[s_se[ei].y] = 1.f / (1.f + expf(-(p + b4v)));
    }
}

// ---------------- launcher ----------------

extern "C" void kernel_launch(void* const* d_in, const int* in_sizes, int n_in,
                              void* d_out, int out_size, void* d_ws, size_t ws_size,
                              hipStream_t stream) {
    const float* x  = (const float*)d_in[0];
    const int*   ei = (const int*)d_in[1];
    const float* W1 = (const float*)d_in[2];
    const float* b1 = (const float*)d_in[3];
    const float* W2 = (const float*)d_in[4];
    const float* b2 = (const float*)d_in[5];
    const float* W3 = (const float*)d_in[6];
    const float* b3 = (const float*)d_in[7];
    const float* W4 = (const float*)d_in[8];
    const float* b4 = (const float*)d_in[9];

    int N = in_sizes[0] / 256;      // 50000
    int E = in_sizes[1] / 2;        // 1.6M

    char* ws = (char*)d_ws;
    size_t off = 0;
    auto alloc = [&](size_t bytes) -> void* {
        void* p = ws + off;
        off += (bytes + 255) & ~(size_t)255;
        return p;
    };
    int*      flag    = (int*)     alloc(256);
    int*      srcn    = (int*)     alloc((size_t)E * 4);
    int*      dstn    = (int*)     alloc((size_t)E * 4);
    int*      deg     = (int*)     alloc((size_t)N * 4);
    int*      offs    = (int*)     alloc((size_t)(N + 1) * 4);
    int*      cursor  = (int*)     alloc((size_t)N * 4);
    float*    dinv    = (float*)   alloc((size_t)N * 4);
    int2*     csr_se  = (int2*)    alloc((size_t)E * 8);
    int*      csr_dst = (int*)     alloc((size_t)E * 4);
    ushort_t* gbuf    = (ushort_t*)alloc((size_t)N * 128 * 2);   // bf16 gather table
    ushort_t* ubuf    = (ushort_t*)alloc((size_t)N * 128 * 2);   // bf16 u table
    ushort_t* vbuf    = (ushort_t*)alloc((size_t)N * 128 * 2);   // bf16 v table
    float*    hbuf    = (float*)   alloc((size_t)N * 128 * 4);   // f32 h (GEMM input)
    ushort_t* Wt1     = (ushort_t*)alloc(128 * 256 * 2);
    ushort_t* Wt2     = (ushort_t*)alloc(128 * 128 * 2);
    ushort_t* Wt3a    = (ushort_t*)alloc(128 * 128 * 2);
    ushort_t* Wt3b    = (ushort_t*)alloc(128 * 128 * 2);
    (void)ws_size; (void)n_in; (void)out_size;

    float* outp = (float*)d_out;
    int gE = (E + 255) / 256;
    int gN4 = (N + 3) / 4;
    int RB = (N + 7) / 8;           // dst-range per XCD

    // dtype hedge + index normalization
    int nwords = (2 * E < 4096) ? 2 * E : 4096;
    detect_i64<<<1, 1024, 0, stream>>>(ei, nwords, flag);
    normalize_idx<<<gE, 256, 0, stream>>>(ei, E, flag, srcn, dstn);
    conv_weights<<<320, 256, 0, stream>>>(W1, W2, W3, Wt1, Wt2, Wt3a, Wt3b);

    // CSR (by dst) + dinv, XCD dst-range partitioned
    zero_i32<<<(N + 255) / 256, 256, 0, stream>>>(deg, N);
    count_deg_part<<<gE * 8, 256, 0, stream>>>(dstn, deg, E, RB);
    scan_kernel<<<1, 1024, 0, stream>>>(deg, offs, cursor, dinv, N);
    fill_csr_part<<<gE * 8, 256, 0, stream>>>(srcn, dstn, cursor, csr_se, E, RB);
    fill_seg<<<gN4, 256, 0, stream>>>(offs, csr_dst, N);

    int gM = (N + 63) / 64;
    // layer 1: g1 = bf16(dinv * (x @ W1));  h1 = relu(dinv*(sum g1) + b1)  [f32]
    gemm_mfma<<<gM, 256, 0, stream>>>(x, Wt1, gbuf, dinv, nullptr, N, 256, 1);
    pull_agg<<<gN4, 256, 0, stream>>>(gbuf, csr_se, offs, dinv, b1, hbuf, N, 1);
    // layer 2: g2 = bf16(dinv * (h1 @ W2)); h2 = dinv*(sum g2) + b2        [f32]
    gemm_mfma<<<gM, 256, 0, stream>>>(hbuf, Wt2, gbuf, dinv, nullptr, N, 128, 1);
    pull_agg<<<gN4, 256, 0, stream>>>(gbuf, csr_se, offs, dinv, b2, hbuf, N, 0);
    // factorized edge MLP: u = bf16(h2 @ W3a), v = bf16(h2 @ W3b + b3)
    gemm_mfma<<<gM, 256, 0, stream>>>(hbuf, Wt3a, ubuf, nullptr, nullptr, N, 128, 1);
    gemm_mfma<<<gM, 256, 0, stream>>>(hbuf, Wt3b, vbuf, nullptr, b3, N, 128, 1);
    // score per edge, CSR order (v-row locality), scatter to original edge id
    edge_score_csr<<<(E + 31) / 32, 256, 0, stream>>>(ubuf, vbuf, csr_se, csr_dst,
                                                      W4, b4, outp, E);
}

// Round 9
// 621.444 us; speedup vs baseline: 1.1696x; 1.0207x over previous
//
#include <hip/hip_runtime.h>
#include <math.h>

typedef unsigned short ushort_t;
typedef __attribute__((ext_vector_type(8))) short bf16x8;
typedef __attribute__((ext_vector_type(8))) unsigned short us8;
typedef __attribute__((ext_vector_type(4))) float f32x4;

__device__ __forceinline__ float bf2f(unsigned short u) {
    union { unsigned int i; float f; } x; x.i = ((unsigned int)u) << 16; return x.f;
}
__device__ __forceinline__ unsigned short f2bf(float f) {
    union { float f; unsigned int i; } x; x.f = f;          // round-to-nearest-even
    unsigned int lsb = (x.i >> 16) & 1u;
    return (unsigned short)((x.i + 0x7fffu + lsb) >> 16);
}

// ---------------- edge_index dtype hedge ----------------

__global__ __launch_bounds__(1024) void detect_i64(const int* __restrict__ ei,
                                                   int nwords, int* __restrict__ flag) {
    __shared__ int s_any;
    if (threadIdx.x == 0) s_any = 0;
    __syncthreads();
    int any = 0;
    for (int i = threadIdx.x; 2 * i + 1 < nwords; i += 1024)
        if (ei[2 * i + 1] != 0) any = 1;
    if (any) s_any = 1;           // race-benign
    __syncthreads();
    if (threadIdx.x == 0) flag[0] = (s_any == 0) ? 1 : 0;   // 1 => int64 layout
}

__global__ __launch_bounds__(256) void normalize_idx(const int* __restrict__ ei, int E,
                                                     const int* __restrict__ flag,
                                                     int* __restrict__ s_out,
                                                     int* __restrict__ d_out) {
    int e = blockIdx.x * 256 + threadIdx.x;
    if (e >= E) return;
    if (flag[0]) {                // int64: element i at int32 word 2i (little-endian)
        s_out[e] = ei[2 * e];
        d_out[e] = ei[2 * (E + e)];
    } else {                      // int32 flat [2][E]
        s_out[e] = ei[e];
        d_out[e] = ei[E + e];
    }
}

// ---------------- CSR build (XCD dst-range partitioned) ----------------
// blockIdx & 7 -> XCD under the %8 round-robin dispatch heuristic. Each XCD
// owns dst range [xcd*RB, xcd*RB+RB): its cursor/deg/csr lines stay in its
// private L2 (no cross-XCD dirty-line multiplication). Perf-only assumption.

__global__ __launch_bounds__(256) void zero_i32(int* __restrict__ p, int n) {
    int i = blockIdx.x * 256 + threadIdx.x;
    if (i < n) p[i] = 0;
}

__global__ __launch_bounds__(256) void count_deg_part(const int* __restrict__ dst,
                                                      int* __restrict__ deg,
                                                      int E, int RB) {
    int xcd = blockIdx.x & 7;
    int e = (blockIdx.x >> 3) * 256 + threadIdx.x;
    if (e >= E) return;
    int d = dst[e];
    if ((unsigned)(d - xcd * RB) < (unsigned)RB) atomicAdd(&deg[d], 1);
}

// single-block exclusive scan over deg -> offs, cursor; also dinv = rsqrt(deg+1)
__global__ __launch_bounds__(1024) void scan_kernel(const int* __restrict__ deg,
                                                    int* __restrict__ offs,
                                                    int* __restrict__ cursor,
                                                    float* __restrict__ dinv, int n) {
    __shared__ int wsum[16];
    __shared__ int s_carry;
    int tid = threadIdx.x, lane = tid & 63, wid = tid >> 6;
    if (tid == 0) s_carry = 0;
    __syncthreads();
    for (int base = 0; base < n; base += 1024) {
        int i = base + tid;
        int v = (i < n) ? deg[i] : 0;
        int x = v;
        #pragma unroll
        for (int d = 1; d < 64; d <<= 1) {
            int y = __shfl_up(x, d, 64);
            if (lane >= d) x += y;
        }
        if (lane == 63) wsum[wid] = x;
        __syncthreads();
        int carry = s_carry;
        __syncthreads();           // everyone read carry before thread0 rewrites
        if (tid == 0) {
            int run = 0;
            #pragma unroll
            for (int w = 0; w < 16; ++w) { int t = wsum[w]; wsum[w] = run; run += t; }
            s_carry = carry + run;
        }
        __syncthreads();
        if (i < n) {
            int excl = carry + wsum[wid] + (x - v);
            offs[i] = excl;
            cursor[i] = excl;
            dinv[i] = rsqrtf((float)(v + 1));   // +1 self loop
        }
        __syncthreads();           // protect wsum before next iteration
    }
    if (tid == 0) offs[n] = s_carry;
}

__global__ __launch_bounds__(256) void fill_csr_part(const int* __restrict__ src,
                                                     const int* __restrict__ dst,
                                                     int* __restrict__ cursor,
                                                     int2* __restrict__ csr_se,
                                                     int E, int RB) {
    int xcd = blockIdx.x & 7;
    int e = (blockIdx.x >> 3) * 256 + threadIdx.x;
    if (e >= E) return;
    int d = dst[e];
    if ((unsigned)(d - xcd * RB) < (unsigned)RB) {
        int pos = atomicAdd(&cursor[d], 1);
        csr_se[pos] = make_int2(src[e], e);
    }
}

// ---------------- weight pre-convert: f32 [K][128] -> bf16 transposed [128][K] ----

__global__ __launch_bounds__(256) void conv_weights(const float* __restrict__ W1,
                                                    const float* __restrict__ W2,
                                                    const float* __restrict__ W3,
                                                    ushort_t* __restrict__ Wt1,
                                                    ushort_t* __restrict__ Wt2,
                                                    ushort_t* __restrict__ Wt3a,
                                                    ushort_t* __restrict__ Wt3b) {
    int t = blockIdx.x * 256 + threadIdx.x;
    if (t < 32768) {                 // W1 [256][128] -> Wt1 [128][256]
        int k = t >> 7, n = t & 127;
        Wt1[n * 256 + k] = f2bf(W1[t]);
    } else if (t < 49152) {          // W2 [128][128]
        int u = t - 32768; int k = u >> 7, n = u & 127;
        Wt2[n * 128 + k] = f2bf(W2[u]);
    } else if (t < 65536) {          // W3a = W3[0:128][:]
        int u = t - 49152; int k = u >> 7, n = u & 127;
        Wt3a[n * 128 + k] = f2bf(W3[u]);
    } else if (t < 81920) {          // W3b = W3[128:256][:]
        int u = t - 65536; int k = u >> 7, n = u & 127;
        Wt3b[n * 128 + k] = f2bf(W3[128 * 128 + u]);
    }
}

// ---------------- bf16 MFMA GEMM (half-K-resident B, packed staging) ----------
// out[m][n] = scale_m * (sum_k A[m][k] W[k][n]) + bias_n
// Fragment mapping identical to the verified round-5/7 kernel (absmax ✓):
// A-frag As[row=lane&15][k=(lane>>4)*8+i], B-frag Bt[col=lane&15][same k],
// C/D col=lane&15, row=(lane>>4)*4+reg (HW-verified m89/m91).

#define ASTR 40    // ushorts per As row (80B: 2-way bank alias on b128 reads = free)
#define BSTR 136   // ushorts per Bt row (272B: 2-way alias = free)

__global__ __launch_bounds__(256) void gemm_mfma(const float* __restrict__ A,
                                                 const ushort_t* __restrict__ Wt,
                                                 void* __restrict__ outv,
                                                 const float* __restrict__ dinv,
                                                 const float* __restrict__ bias,
                                                 int M, int K, int out_bf16) {
    __shared__ __attribute__((aligned(16))) ushort_t Bt[128 * BSTR]; // [col][k-kh]
    __shared__ __attribute__((aligned(16))) ushort_t As[64 * ASTR];  // [row][k-k0]
    int tid = threadIdx.x;
    int wave = tid >> 6, lane = tid & 63;
    int l15 = lane & 15, lg = lane >> 4;
    int block_m = blockIdx.x * 64;
    f32x4 acc[8];
    #pragma unroll
    for (int i = 0; i < 8; ++i) acc[i] = (f32x4){0.f, 0.f, 0.f, 0.f};

    for (int kh = 0; kh < K; kh += 128) {
        // stage B half: 128 cols x 128 k, pure ushort4 copy (16 per thread)
        #pragma unroll
        for (int i = 0; i < 16; ++i) {
            int u = i * 256 + tid;             // ushort4 unit
            int col = u >> 5;                  // 32 quads per col
            int kq = (u & 31) * 4;
            ushort4 w = *(const ushort4*)(&Wt[(size_t)col * K + kh + kq]);
            *(ushort4*)(&Bt[col * BSTR + kq]) = w;
        }
        for (int k0 = kh; k0 < kh + 128; k0 += 32) {
            // stage A: 64 rows x 32 k, packed ushort4 stores (2 per thread)
            #pragma unroll
            for (int rep = 0; rep < 2; ++rep) {
                int unit = rep * 256 + tid;
                int r = unit >> 3;             // 0..63
                int kc = (unit & 7) * 4;       // 0..28
                int gr = block_m + r;
                int grc = gr < M ? gr : M - 1;
                float4 v = *(const float4*)(&A[(size_t)grc * K + k0 + kc]);
                if (gr >= M) v = make_float4(0.f, 0.f, 0.f, 0.f);
                ushort4 p;
                p.x = f2bf(v.x); p.y = f2bf(v.y); p.z = f2bf(v.z); p.w = f2bf(v.w);
                *(ushort4*)(&As[r * ASTR + kc]) = p;
            }
            __syncthreads();
            bf16x8 af = *(const bf16x8*)(&As[(wave * 16 + l15) * ASTR + lg * 8]);
            #pragma unroll
            for (int nf = 0; nf < 8; ++nf) {
                bf16x8 bf = *(const bf16x8*)(&Bt[(nf * 16 + l15) * BSTR +
                                                 (k0 - kh) + lg * 8]);
                acc[nf] = __builtin_amdgcn_mfma_f32_16x16x32_bf16(af, bf, acc[nf],
                                                                  0, 0, 0);
            }
            __syncthreads();
        }
    }
    int orow = block_m + wave * 16 + lg * 4;
    #pragma unroll
    for (int nf = 0; nf < 8; ++nf) {
        int col = nf * 16 + l15;
        float bb = bias ? bias[col] : 0.f;
        #pragma unroll
        for (int j = 0; j < 4; ++j) {
            int m = orow + j;
            if (m < M) {
                float s = dinv ? dinv[m] : 1.f;
                float o = acc[nf][j] * s + bb;
                if (out_bf16)
                    ((ushort_t*)outv)[(size_t)m * 128 + col] = f2bf(o);
                else
                    ((float*)outv)[(size_t)m * 128 + col] = o;
            }
        }
    }
}

// ---------------- pull aggregation: 4 neighbors per wave-iteration ----------------
// out[n] = act( dinv[n]*(g[n] + sum_{i in CSR[n]} g[src_i]) + bias )
// 64 lanes per node: quad q=lane>>4 takes neighbor i+q, cols 8c..8c+7 (c=lane&15,
// us8 = 16 B/lane). Tail slots read the zero row (index n_nodes). Quad-combine
// via shfl_xor 16,32; lanes 0-15 store the f32 row.

__global__ __launch_bounds__(256) void pull_agg(const ushort_t* __restrict__ g,
                                                const int2* __restrict__ csr_se,
                                                const int* __restrict__ offs,
                                                const float* __restrict__ dinv,
                                                const float* __restrict__ bias,
                                                float* __restrict__ out,
                                                int n_nodes, int do_relu) {
    int tid = threadIdx.x;
    int wid = tid >> 6, lane = tid & 63;
    int q = lane >> 4, c = lane & 15;
    int node = blockIdx.x * 4 + wid;
    if (node >= n_nodes) return;
    int beg = offs[node], end = offs[node + 1];
    float acc[8] = {};
    for (int i = beg; i < end; i += 4) {
        int j = i + q;
        int sidx = (j < end) ? csr_se[j].x : n_nodes;   // zero row when invalid
        us8 r = *(const us8*)(g + (size_t)sidx * 128 + c * 8);
        acc[0] += bf2f(r[0]); acc[1] += bf2f(r[1]);
        acc[2] += bf2f(r[2]); acc[3] += bf2f(r[3]);
        acc[4] += bf2f(r[4]); acc[5] += bf2f(r[5]);
        acc[6] += bf2f(r[6]); acc[7] += bf2f(r[7]);
    }
    #pragma unroll
    for (int k = 0; k < 8; ++k) {
        acc[k] += __shfl_xor(acc[k], 16, 64);
        acc[k] += __shfl_xor(acc[k], 32, 64);
    }
    // self-loop row
    us8 sr = *(const us8*)(g + (size_t)node * 128 + c * 8);
    float s = dinv[node];
    float4 ba = *(const float4*)(&bias[c * 8]);
    float4 bb = *(const float4*)(&bias[c * 8 + 4]);
    float o[8];
    o[0] = (acc[0] + bf2f(sr[0])) * s + ba.x;
    o[1] = (acc[1] + bf2f(sr[1])) * s + ba.y;
    o[2] = (acc[2] + bf2f(sr[2])) * s + ba.z;
    o[3] = (acc[3] + bf2f(sr[3])) * s + ba.w;
    o[4] = (acc[4] + bf2f(sr[4])) * s + bb.x;
    o[5] = (acc[5] + bf2f(sr[5])) * s + bb.y;
    o[6] = (acc[6] + bf2f(sr[6])) * s + bb.z;
    o[7] = (acc[7] + bf2f(sr[7])) * s + bb.w;
    if (do_relu) {
        #pragma unroll
        for (int k = 0; k < 8; ++k) o[k] = fmaxf(o[k], 0.f);
    }
    if (q == 0) {
        float* op = &out[(size_t)node * 128 + c * 8];
        *(float4*)op = make_float4(o[0], o[1], o[2], o[3]);
        *(float4*)(op + 4) = make_float4(o[4], o[5], o[6], o[7]);
    }
}

// ---------------- edge scorer: dst-segment form ----------------
// score[eid] = sigmoid( sum_j relu(u[s][j] + v[d][j]) * W4[j] + b4 )
// One 16-lane group per dst node: v[d] (+b3 folded) and W4 live in registers;
// per edge only u[src] is gathered (us8, 16 B/lane). 4-stage shuffle reduce.

__global__ __launch_bounds__(256) void edge_score_seg(const ushort_t* __restrict__ u,
                                                      const ushort_t* __restrict__ v,
                                                      const int2* __restrict__ csr_se,
                                                      const int* __restrict__ offs,
                                                      const float* __restrict__ W4,
                                                      const float* __restrict__ b4,
                                                      float* __restrict__ out,
                                                      int n_nodes) {
    int tid = threadIdx.x;
    int grp = tid >> 4, c = tid & 15;
    int node = blockIdx.x * 16 + grp;
    if (node >= n_nodes) return;
    int beg = offs[node], end = offs[node + 1];
    if (beg == end) return;
    us8 vv = *(const us8*)(v + (size_t)node * 128 + c * 8);
    float vr[8];
    #pragma unroll
    for (int k = 0; k < 8; ++k) vr[k] = bf2f(vv[k]);
    float4 wa = *(const float4*)(&W4[c * 8]);
    float4 wb = *(const float4*)(&W4[c * 8 + 4]);
    float b4v = b4[0];
    for (int p = beg; p < end; ++p) {
        int2 se = csr_se[p];
        us8 uu = *(const us8*)(u + (size_t)se.x * 128 + c * 8);
        float ps;
        ps  = fmaxf(bf2f(uu[0]) + vr[0], 0.f) * wa.x;
        ps += fmaxf(bf2f(uu[1]) + vr[1], 0.f) * wa.y;
        ps += fmaxf(bf2f(uu[2]) + vr[2], 0.f) * wa.z;
        ps += fmaxf(bf2f(uu[3]) + vr[3], 0.f) * wa.w;
        ps += fmaxf(bf2f(uu[4]) + vr[4], 0.f) * wb.x;
        ps += fmaxf(bf2f(uu[5]) + vr[5], 0.f) * wb.y;
        ps += fmaxf(bf2f(uu[6]) + vr[6], 0.f) * wb.z;
        ps += fmaxf(bf2f(uu[7]) + vr[7], 0.f) * wb.w;
        ps += __shfl_xor(ps, 8, 64);
        ps += __shfl_xor(ps, 4, 64);
        ps += __shfl_xor(ps, 2, 64);
        ps += __shfl_xor(ps, 1, 64);
        if (c == 0)
            out[se.y] = 1.f / (1.f + expf(-(ps + b4v)));
    }
}

// ---------------- launcher ----------------

extern "C" void kernel_launch(void* const* d_in, const int* in_sizes, int n_in,
                              void* d_out, int out_size, void* d_ws, size_t ws_size,
                              hipStream_t stream) {
    const float* x  = (const float*)d_in[0];
    const int*   ei = (const int*)d_in[1];
    const float* W1 = (const float*)d_in[2];
    const float* b1 = (const float*)d_in[3];
    const float* W2 = (const float*)d_in[4];
    const float* b2 = (const float*)d_in[5];
    const float* W3 = (const float*)d_in[6];
    const float* b3 = (const float*)d_in[7];
    const float* W4 = (const float*)d_in[8];
    const float* b4 = (const float*)d_in[9];

    int N = in_sizes[0] / 256;      // 50000
    int E = in_sizes[1] / 2;        // 1.6M

    char* ws = (char*)d_ws;
    size_t off = 0;
    auto alloc = [&](size_t bytes) -> void* {
        void* p = ws + off;
        off += (bytes + 255) & ~(size_t)255;
        return p;
    };
    int*      flag    = (int*)     alloc(256);
    int*      srcn    = (int*)     alloc((size_t)E * 4);
    int*      dstn    = (int*)     alloc((size_t)E * 4);
    int*      deg     = (int*)     alloc((size_t)N * 4);
    int*      offs    = (int*)     alloc((size_t)(N + 1) * 4);
    int*      cursor  = (int*)     alloc((size_t)N * 4);
    float*    dinv    = (float*)   alloc((size_t)N * 4);
    int2*     csr_se  = (int2*)    alloc((size_t)E * 8);
    ushort_t* gbuf    = (ushort_t*)alloc((size_t)(N + 1) * 128 * 2); // + zero row
    ushort_t* ubuf    = (ushort_t*)alloc((size_t)N * 128 * 2);       // bf16 u table
    ushort_t* vbuf    = (ushort_t*)alloc((size_t)N * 128 * 2);       // bf16 v table
    float*    hbuf    = (float*)   alloc((size_t)N * 128 * 4);       // f32 h
    ushort_t* Wt1     = (ushort_t*)alloc(128 * 256 * 2);
    ushort_t* Wt2     = (ushort_t*)alloc(128 * 128 * 2);
    ushort_t* Wt3a    = (ushort_t*)alloc(128 * 128 * 2);
    ushort_t* Wt3b    = (ushort_t*)alloc(128 * 128 * 2);
    (void)ws_size; (void)n_in; (void)out_size;

    float* outp = (float*)d_out;
    int gE = (E + 255) / 256;
    int gN4 = (N + 3) / 4;
    int RB = (N + 7) / 8;           // dst-range per XCD

    // dtype hedge + index normalization
    int nwords = (2 * E < 4096) ? 2 * E : 4096;
    detect_i64<<<1, 1024, 0, stream>>>(ei, nwords, flag);
    normalize_idx<<<gE, 256, 0, stream>>>(ei, E, flag, srcn, dstn);
    conv_weights<<<320, 256, 0, stream>>>(W1, W2, W3, Wt1, Wt2, Wt3a, Wt3b);

    // CSR (by dst) + dinv, XCD dst-range partitioned; zero the padding row of gbuf
    zero_i32<<<(N + 255) / 256, 256, 0, stream>>>(deg, N);
    zero_i32<<<1, 256, 0, stream>>>((int*)(gbuf + (size_t)N * 128), 64);
    count_deg_part<<<gE * 8, 256, 0, stream>>>(dstn, deg, E, RB);
    scan_kernel<<<1, 1024, 0, stream>>>(deg, offs, cursor, dinv, N);
    fill_csr_part<<<gE * 8, 256, 0, stream>>>(srcn, dstn, cursor, csr_se, E, RB);

    int gM = (N + 63) / 64;
    // layer 1: g1 = bf16(dinv * (x @ W1));  h1 = relu(dinv*(sum g1) + b1)  [f32]
    gemm_mfma<<<gM, 256, 0, stream>>>(x, Wt1, gbuf, dinv, nullptr, N, 256, 1);
    pull_agg<<<gN4, 256, 0, stream>>>(gbuf, csr_se, offs, dinv, b1, hbuf, N, 1);
    // layer 2: g2 = bf16(dinv * (h1 @ W2)); h2 = dinv*(sum g2) + b2        [f32]
    gemm_mfma<<<gM, 256, 0, stream>>>(hbuf, Wt2, gbuf, dinv, nullptr, N, 128, 1);
    pull_agg<<<gN4, 256, 0, stream>>>(gbuf, csr_se, offs, dinv, b2, hbuf, N, 0);
    // factorized edge MLP: u = bf16(h2 @ W3a), v = bf16(h2 @ W3b + b3)
    gemm_mfma<<<gM, 256, 0, stream>>>(hbuf, Wt3a, ubuf, nullptr, nullptr, N, 128, 1);
    gemm_mfma<<<gM, 256, 0, stream>>>(hbuf, Wt3b, vbuf, nullptr, b3, N, 128, 1);
    // score per edge: dst-segment order, v in registers, scatter to edge id
    edge_score_seg<<<(N + 15) / 16, 256, 0, stream>>>(ubuf, vbuf, csr_se, offs,
                                                      W4, b4, outp, N);
}

// Round 10
// 582.423 us; speedup vs baseline: 1.2480x; 1.0670x over previous
//
#include <hip/hip_runtime.h>
#include <math.h>

typedef unsigned short ushort_t;
typedef __attribute__((ext_vector_type(8))) short bf16x8;
typedef __attribute__((ext_vector_type(8))) unsigned short us8;
typedef __attribute__((ext_vector_type(4))) float f32x4;

__device__ __forceinline__ float bf2f(unsigned short u) {
    union { unsigned int i; float f; } x; x.i = ((unsigned int)u) << 16; return x.f;
}
__device__ __forceinline__ unsigned short f2bf(float f) {
    union { float f; unsigned int i; } x; x.f = f;          // round-to-nearest-even
    unsigned int lsb = (x.i >> 16) & 1u;
    return (unsigned short)((x.i + 0x7fffu + lsb) >> 16);
}

// ---------------- edge_index dtype hedge ----------------

__global__ __launch_bounds__(1024) void detect_i64(const int* __restrict__ ei,
                                                   int nwords, int* __restrict__ flag) {
    __shared__ int s_any;
    if (threadIdx.x == 0) s_any = 0;
    __syncthreads();
    int any = 0;
    for (int i = threadIdx.x; 2 * i + 1 < nwords; i += 1024)
        if (ei[2 * i + 1] != 0) any = 1;
    if (any) s_any = 1;           // race-benign
    __syncthreads();
    if (threadIdx.x == 0) flag[0] = (s_any == 0) ? 1 : 0;   // 1 => int64 layout
}

__global__ __launch_bounds__(256) void normalize_idx(const int* __restrict__ ei, int E,
                                                     const int* __restrict__ flag,
                                                     int* __restrict__ s_out,
                                                     int* __restrict__ d_out) {
    int e = blockIdx.x * 256 + threadIdx.x;
    if (e >= E) return;
    if (flag[0]) {                // int64: element i at int32 word 2i (little-endian)
        s_out[e] = ei[2 * e];
        d_out[e] = ei[2 * (E + e)];
    } else {                      // int32 flat [2][E]
        s_out[e] = ei[e];
        d_out[e] = ei[E + e];
    }
}

// ---------------- CSR build (XCD dst-range partitioned) ----------------
// blockIdx & 7 -> XCD under the %8 round-robin dispatch heuristic. Each XCD
// owns dst range [xcd*RB, xcd*RB+RB): its cursor/deg/csr lines stay in its
// private L2 (no cross-XCD dirty-line multiplication). Perf-only assumption.

__global__ __launch_bounds__(256) void zero_i32(int* __restrict__ p, int n) {
    int i = blockIdx.x * 256 + threadIdx.x;
    if (i < n) p[i] = 0;
}

__global__ __launch_bounds__(256) void count_deg_part(const int* __restrict__ dst,
                                                      int* __restrict__ deg,
                                                      int E, int RB) {
    int xcd = blockIdx.x & 7;
    int e = (blockIdx.x >> 3) * 256 + threadIdx.x;
    if (e >= E) return;
    int d = dst[e];
    if ((unsigned)(d - xcd * RB) < (unsigned)RB) atomicAdd(&deg[d], 1);
}

// single-block exclusive scan over deg -> offs, cursor; also dinv = rsqrt(deg+1)
__global__ __launch_bounds__(1024) void scan_kernel(const int* __restrict__ deg,
                                                    int* __restrict__ offs,
                                                    int* __restrict__ cursor,
                                                    float* __restrict__ dinv, int n) {
    __shared__ int wsum[16];
    __shared__ int s_carry;
    int tid = threadIdx.x, lane = tid & 63, wid = tid >> 6;
    if (tid == 0) s_carry = 0;
    __syncthreads();
    for (int base = 0; base < n; base += 1024) {
        int i = base + tid;
        int v = (i < n) ? deg[i] : 0;
        int x = v;
        #pragma unroll
        for (int d = 1; d < 64; d <<= 1) {
            int y = __shfl_up(x, d, 64);
            if (lane >= d) x += y;
        }
        if (lane == 63) wsum[wid] = x;
        __syncthreads();
        int carry = s_carry;
        __syncthreads();           // everyone read carry before thread0 rewrites
        if (tid == 0) {
            int run = 0;
            #pragma unroll
            for (int w = 0; w < 16; ++w) { int t = wsum[w]; wsum[w] = run; run += t; }
            s_carry = carry + run;
        }
        __syncthreads();
        if (i < n) {
            int excl = carry + wsum[wid] + (x - v);
            offs[i] = excl;
            cursor[i] = excl;
            dinv[i] = rsqrtf((float)(v + 1));   // +1 self loop
        }
        __syncthreads();           // protect wsum before next iteration
    }
    if (tid == 0) offs[n] = s_carry;
}

__global__ __launch_bounds__(256) void fill_csr_part(const int* __restrict__ src,
                                                     const int* __restrict__ dst,
                                                     int* __restrict__ cursor,
                                                     int2* __restrict__ csr_se,
                                                     int E, int RB) {
    int xcd = blockIdx.x & 7;
    int e = (blockIdx.x >> 3) * 256 + threadIdx.x;
    if (e >= E) return;
    int d = dst[e];
    if ((unsigned)(d - xcd * RB) < (unsigned)RB) {
        int pos = atomicAdd(&cursor[d], 1);
        csr_se[pos] = make_int2(src[e], e);
    }
}

// ---------------- weight pre-convert: f32 [K][128] -> bf16 transposed [128][K] ----

__global__ __launch_bounds__(256) void conv_weights(const float* __restrict__ W1,
                                                    const float* __restrict__ W2,
                                                    const float* __restrict__ W3,
                                                    ushort_t* __restrict__ Wt1,
                                                    ushort_t* __restrict__ Wt2,
                                                    ushort_t* __restrict__ Wt3a,
                                                    ushort_t* __restrict__ Wt3b) {
    int t = blockIdx.x * 256 + threadIdx.x;
    if (t < 32768) {                 // W1 [256][128] -> Wt1 [128][256]
        int k = t >> 7, n = t & 127;
        Wt1[n * 256 + k] = f2bf(W1[t]);
    } else if (t < 49152) {          // W2 [128][128]
        int u = t - 32768; int k = u >> 7, n = u & 127;
        Wt2[n * 128 + k] = f2bf(W2[u]);
    } else if (t < 65536) {          // W3a = W3[0:128][:]
        int u = t - 49152; int k = u >> 7, n = u & 127;
        Wt3a[n * 128 + k] = f2bf(W3[u]);
    } else if (t < 81920) {          // W3b = W3[128:256][:]
        int u = t - 65536; int k = u >> 7, n = u & 127;
        Wt3b[n * 128 + k] = f2bf(W3[128 * 128 + u]);
    }
}

// ---------------- bf16 MFMA GEMM (half-K-resident B, packed staging) ----------
// out[m][n] = scale_m * (sum_k A[m][k] W[k][n]) + bias_n
// Fragment mapping identical to the verified round-5/7 kernel (absmax ✓):
// A-frag As[row=lane&15][k=(lane>>4)*8+i], B-frag Bt[col=lane&15][same k],
// C/D col=lane&15, row=(lane>>4)*4+reg (HW-verified m89/m91).

#define ASTR 40    // ushorts per As row (80B: 2-way bank alias on b128 reads = free)
#define BSTR 136   // ushorts per Bt row (272B: 2-way alias = free)

__global__ __launch_bounds__(256) void gemm_mfma(const float* __restrict__ A,
                                                 const ushort_t* __restrict__ Wt,
                                                 void* __restrict__ outv,
                                                 const float* __restrict__ dinv,
                                                 const float* __restrict__ bias,
                                                 int M, int K, int out_bf16) {
    __shared__ __attribute__((aligned(16))) ushort_t Bt[128 * BSTR]; // [col][k-kh]
    __shared__ __attribute__((aligned(16))) ushort_t As[64 * ASTR];  // [row][k-k0]
    int tid = threadIdx.x;
    int wave = tid >> 6, lane = tid & 63;
    int l15 = lane & 15, lg = lane >> 4;
    int block_m = blockIdx.x * 64;
    f32x4 acc[8];
    #pragma unroll
    for (int i = 0; i < 8; ++i) acc[i] = (f32x4){0.f, 0.f, 0.f, 0.f};

    for (int kh = 0; kh < K; kh += 128) {
        // stage B half: 128 cols x 128 k, pure ushort4 copy (16 per thread)
        #pragma unroll
        for (int i = 0; i < 16; ++i) {
            int u = i * 256 + tid;             // ushort4 unit
            int col = u >> 5;                  // 32 quads per col
            int kq = (u & 31) * 4;
            ushort4 w = *(const ushort4*)(&Wt[(size_t)col * K + kh + kq]);
            *(ushort4*)(&Bt[col * BSTR + kq]) = w;
        }
        for (int k0 = kh; k0 < kh + 128; k0 += 32) {
            // stage A: 64 rows x 32 k, packed ushort4 stores (2 per thread)
            #pragma unroll
            for (int rep = 0; rep < 2; ++rep) {
                int unit = rep * 256 + tid;
                int r = unit >> 3;             // 0..63
                int kc = (unit & 7) * 4;       // 0..28
                int gr = block_m + r;
                int grc = gr < M ? gr : M - 1;
                float4 v = *(const float4*)(&A[(size_t)grc * K + k0 + kc]);
                if (gr >= M) v = make_float4(0.f, 0.f, 0.f, 0.f);
                ushort4 p;
                p.x = f2bf(v.x); p.y = f2bf(v.y); p.z = f2bf(v.z); p.w = f2bf(v.w);
                *(ushort4*)(&As[r * ASTR + kc]) = p;
            }
            __syncthreads();
            bf16x8 af = *(const bf16x8*)(&As[(wave * 16 + l15) * ASTR + lg * 8]);
            #pragma unroll
            for (int nf = 0; nf < 8; ++nf) {
                bf16x8 bf = *(const bf16x8*)(&Bt[(nf * 16 + l15) * BSTR +
                                                 (k0 - kh) + lg * 8]);
                acc[nf] = __builtin_amdgcn_mfma_f32_16x16x32_bf16(af, bf, acc[nf],
                                                                  0, 0, 0);
            }
            __syncthreads();
        }
    }
    int orow = block_m + wave * 16 + lg * 4;
    #pragma unroll
    for (int nf = 0; nf < 8; ++nf) {
        int col = nf * 16 + l15;
        float bb = bias ? bias[col] : 0.f;
        #pragma unroll
        for (int j = 0; j < 4; ++j) {
            int m = orow + j;
            if (m < M) {
                float s = dinv ? dinv[m] : 1.f;
                float o = acc[nf][j] * s + bb;
                if (out_bf16)
                    ((ushort_t*)outv)[(size_t)m * 128 + col] = f2bf(o);
                else
                    ((float*)outv)[(size_t)m * 128 + col] = o;
            }
        }
    }
}

// ---------------- pull aggregation: 8 neighbors in flight per wave ----------------
// out[n] = act( dinv[n]*(g[n] + sum_{i in CSR[n]} g[src_i]) + bias )
// 64 lanes per node: quad q=lane>>4 takes neighbors i+q / i+4+q (us8 16 B/lane).
// Main loop (i+8 <= end) is validity-check-free; step-4 tail uses the zero row.
// Accumulation order per lane identical to the non-unrolled form.

__global__ __launch_bounds__(256) void pull_agg(const ushort_t* __restrict__ g,
                                                const int2* __restrict__ csr_se,
                                                const int* __restrict__ offs,
                                                const float* __restrict__ dinv,
                                                const float* __restrict__ bias,
                                                float* __restrict__ out,
                                                int n_nodes, int do_relu) {
    int tid = threadIdx.x;
    int wid = tid >> 6, lane = tid & 63;
    int q = lane >> 4, c = lane & 15;
    int node = blockIdx.x * 4 + wid;
    if (node >= n_nodes) return;
    int beg = offs[node], end = offs[node + 1];
    float acc[8] = {};
    int i = beg;
    for (; i + 8 <= end; i += 8) {
        int s1 = csr_se[i + q].x;
        int s2 = csr_se[i + 4 + q].x;
        us8 r1 = *(const us8*)(g + (size_t)s1 * 128 + c * 8);
        us8 r2 = *(const us8*)(g + (size_t)s2 * 128 + c * 8);
        acc[0] += bf2f(r1[0]); acc[1] += bf2f(r1[1]);
        acc[2] += bf2f(r1[2]); acc[3] += bf2f(r1[3]);
        acc[4] += bf2f(r1[4]); acc[5] += bf2f(r1[5]);
        acc[6] += bf2f(r1[6]); acc[7] += bf2f(r1[7]);
        acc[0] += bf2f(r2[0]); acc[1] += bf2f(r2[1]);
        acc[2] += bf2f(r2[2]); acc[3] += bf2f(r2[3]);
        acc[4] += bf2f(r2[4]); acc[5] += bf2f(r2[5]);
        acc[6] += bf2f(r2[6]); acc[7] += bf2f(r2[7]);
    }
    for (; i < end; i += 4) {
        int j = i + q;
        int sidx = (j < end) ? csr_se[j].x : n_nodes;   // zero row when invalid
        us8 r = *(const us8*)(g + (size_t)sidx * 128 + c * 8);
        acc[0] += bf2f(r[0]); acc[1] += bf2f(r[1]);
        acc[2] += bf2f(r[2]); acc[3] += bf2f(r[3]);
        acc[4] += bf2f(r[4]); acc[5] += bf2f(r[5]);
        acc[6] += bf2f(r[6]); acc[7] += bf2f(r[7]);
    }
    #pragma unroll
    for (int k = 0; k < 8; ++k) {
        acc[k] += __shfl_xor(acc[k], 16, 64);
        acc[k] += __shfl_xor(acc[k], 32, 64);
    }
    // self-loop row
    us8 sr = *(const us8*)(g + (size_t)node * 128 + c * 8);
    float s = dinv[node];
    float4 ba = *(const float4*)(&bias[c * 8]);
    float4 bb = *(const float4*)(&bias[c * 8 + 4]);
    float o[8];
    o[0] = (acc[0] + bf2f(sr[0])) * s + ba.x;
    o[1] = (acc[1] + bf2f(sr[1])) * s + ba.y;
    o[2] = (acc[2] + bf2f(sr[2])) * s + ba.z;
    o[3] = (acc[3] + bf2f(sr[3])) * s + ba.w;
    o[4] = (acc[4] + bf2f(sr[4])) * s + bb.x;
    o[5] = (acc[5] + bf2f(sr[5])) * s + bb.y;
    o[6] = (acc[6] + bf2f(sr[6])) * s + bb.z;
    o[7] = (acc[7] + bf2f(sr[7])) * s + bb.w;
    if (do_relu) {
        #pragma unroll
        for (int k = 0; k < 8; ++k) o[k] = fmaxf(o[k], 0.f);
    }
    if (q == 0) {
        float* op = &out[(size_t)node * 128 + c * 8];
        *(float4*)op = make_float4(o[0], o[1], o[2], o[3]);
        *(float4*)(op + 4) = make_float4(o[4], o[5], o[6], o[7]);
    }
}

// ---------------- edge scorer: dst-segment form, 4-edge ILP ----------------
// score[eid] = sigmoid( sum_j relu(u[s][j] + v[d][j]) * W4[j] + b4 )
// One 16-lane group per dst node; v[d] and W4 in registers. Segment loop
// unrolled x4: 4 independent csr_se + u-row loads in flight per group.

__device__ __forceinline__ float edot8(const us8& uu, const float* vr,
                                       const float4& wa, const float4& wb) {
    float ps;
    ps  = fmaxf(bf2f(uu[0]) + vr[0], 0.f) * wa.x;
    ps += fmaxf(bf2f(uu[1]) + vr[1], 0.f) * wa.y;
    ps += fmaxf(bf2f(uu[2]) + vr[2], 0.f) * wa.z;
    ps += fmaxf(bf2f(uu[3]) + vr[3], 0.f) * wa.w;
    ps += fmaxf(bf2f(uu[4]) + vr[4], 0.f) * wb.x;
    ps += fmaxf(bf2f(uu[5]) + vr[5], 0.f) * wb.y;
    ps += fmaxf(bf2f(uu[6]) + vr[6], 0.f) * wb.z;
    ps += fmaxf(bf2f(uu[7]) + vr[7], 0.f) * wb.w;
    ps += __shfl_xor(ps, 8, 64);
    ps += __shfl_xor(ps, 4, 64);
    ps += __shfl_xor(ps, 2, 64);
    ps += __shfl_xor(ps, 1, 64);
    return ps;
}

__global__ __launch_bounds__(256) void edge_score_seg(const ushort_t* __restrict__ u,
                                                      const ushort_t* __restrict__ v,
                                                      const int2* __restrict__ csr_se,
                                                      const int* __restrict__ offs,
                                                      const float* __restrict__ W4,
                                                      const float* __restrict__ b4,
                                                      float* __restrict__ out,
                                                      int n_nodes) {
    int tid = threadIdx.x;
    int grp = tid >> 4, c = tid & 15;
    int node = blockIdx.x * 16 + grp;
    if (node >= n_nodes) return;
    int beg = offs[node], end = offs[node + 1];
    if (beg == end) return;
    us8 vv = *(const us8*)(v + (size_t)node * 128 + c * 8);
    float vr[8];
    #pragma unroll
    for (int k = 0; k < 8; ++k) vr[k] = bf2f(vv[k]);
    float4 wa = *(const float4*)(&W4[c * 8]);
    float4 wb = *(const float4*)(&W4[c * 8 + 4]);
    float b4v = b4[0];
    int p = beg;
    for (; p + 4 <= end; p += 4) {
        int2 se0 = csr_se[p];
        int2 se1 = csr_se[p + 1];
        int2 se2 = csr_se[p + 2];
        int2 se3 = csr_se[p + 3];
        us8 u0 = *(const us8*)(u + (size_t)se0.x * 128 + c * 8);
        us8 u1 = *(const us8*)(u + (size_t)se1.x * 128 + c * 8);
        us8 u2 = *(const us8*)(u + (size_t)se2.x * 128 + c * 8);
        us8 u3 = *(const us8*)(u + (size_t)se3.x * 128 + c * 8);
        float p0 = edot8(u0, vr, wa, wb);
        float p1 = edot8(u1, vr, wa, wb);
        float p2 = edot8(u2, vr, wa, wb);
        float p3 = edot8(u3, vr, wa, wb);
        if (c == 0) {
            out[se0.y] = 1.f / (1.f + expf(-(p0 + b4v)));
            out[se1.y] = 1.f / (1.f + expf(-(p1 + b4v)));
            out[se2.y] = 1.f / (1.f + expf(-(p2 + b4v)));
            out[se3.y] = 1.f / (1.f + expf(-(p3 + b4v)));
        }
    }
    for (; p < end; ++p) {
        int2 se = csr_se[p];
        us8 uu = *(const us8*)(u + (size_t)se.x * 128 + c * 8);
        float ps = edot8(uu, vr, wa, wb);
        if (c == 0)
            out[se.y] = 1.f / (1.f + expf(-(ps + b4v)));
    }
}

// ---------------- launcher ----------------

extern "C" void kernel_launch(void* const* d_in, const int* in_sizes, int n_in,
                              void* d_out, int out_size, void* d_ws, size_t ws_size,
                              hipStream_t stream) {
    const float* x  = (const float*)d_in[0];
    const int*   ei = (const int*)d_in[1];
    const float* W1 = (const float*)d_in[2];
    const float* b1 = (const float*)d_in[3];
    const float* W2 = (const float*)d_in[4];
    const float* b2 = (const float*)d_in[5];
    const float* W3 = (const float*)d_in[6];
    const float* b3 = (const float*)d_in[7];
    const float* W4 = (const float*)d_in[8];
    const float* b4 = (const float*)d_in[9];

    int N = in_sizes[0] / 256;      // 50000
    int E = in_sizes[1] / 2;        // 1.6M

    char* ws = (char*)d_ws;
    size_t off = 0;
    auto alloc = [&](size_t bytes) -> void* {
        void* p = ws + off;
        off += (bytes + 255) & ~(size_t)255;
        return p;
    };
    int*      flag    = (int*)     alloc(256);
    int*      srcn    = (int*)     alloc((size_t)E * 4);
    int*      dstn    = (int*)     alloc((size_t)E * 4);
    int*      deg     = (int*)     alloc((size_t)N * 4);
    int*      offs    = (int*)     alloc((size_t)(N + 1) * 4);
    int*      cursor  = (int*)     alloc((size_t)N * 4);
    float*    dinv    = (float*)   alloc((size_t)N * 4);
    int2*     csr_se  = (int2*)    alloc((size_t)E * 8);
    ushort_t* gbuf    = (ushort_t*)alloc((size_t)(N + 1) * 128 * 2); // + zero row
    ushort_t* ubuf    = (ushort_t*)alloc((size_t)N * 128 * 2);       // bf16 u table
    ushort_t* vbuf    = (ushort_t*)alloc((size_t)N * 128 * 2);       // bf16 v table
    float*    hbuf    = (float*)   alloc((size_t)N * 128 * 4);       // f32 h
    ushort_t* Wt1     = (ushort_t*)alloc(128 * 256 * 2);
    ushort_t* Wt2     = (ushort_t*)alloc(128 * 128 * 2);
    ushort_t* Wt3a    = (ushort_t*)alloc(128 * 128 * 2);
    ushort_t* Wt3b    = (ushort_t*)alloc(128 * 128 * 2);
    (void)ws_size; (void)n_in; (void)out_size;

    float* outp = (float*)d_out;
    int gE = (E + 255) / 256;
    int gN4 = (N + 3) / 4;
    int RB = (N + 7) / 8;           // dst-range per XCD

    // dtype hedge + index normalization
    int nwords = (2 * E < 4096) ? 2 * E : 4096;
    detect_i64<<<1, 1024, 0, stream>>>(ei, nwords, flag);
    normalize_idx<<<gE, 256, 0, stream>>>(ei, E, flag, srcn, dstn);
    conv_weights<<<320, 256, 0, stream>>>(W1, W2, W3, Wt1, Wt2, Wt3a, Wt3b);

    // CSR (by dst) + dinv, XCD dst-range partitioned; zero the padding row of gbuf
    zero_i32<<<(N + 255) / 256, 256, 0, stream>>>(deg, N);
    zero_i32<<<1, 256, 0, stream>>>((int*)(gbuf + (size_t)N * 128), 64);
    count_deg_part<<<gE * 8, 256, 0, stream>>>(dstn, deg, E, RB);
    scan_kernel<<<1, 1024, 0, stream>>>(deg, offs, cursor, dinv, N);
    fill_csr_part<<<gE * 8, 256, 0, stream>>>(srcn, dstn, cursor, csr_se, E, RB);

    int gM = (N + 63) / 64;
    // layer 1: g1 = bf16(dinv * (x @ W1));  h1 = relu(dinv*(sum g1) + b1)  [f32]
    gemm_mfma<<<gM, 256, 0, stream>>>(x, Wt1, gbuf, dinv, nullptr, N, 256, 1);
    pull_agg<<<gN4, 256, 0, stream>>>(gbuf, csr_se, offs, dinv, b1, hbuf, N, 1);
    // layer 2: g2 = bf16(dinv * (h1 @ W2)); h2 = dinv*(sum g2) + b2        [f32]
    gemm_mfma<<<gM, 256, 0, stream>>>(hbuf, Wt2, gbuf, dinv, nullptr, N, 128, 1);
    pull_agg<<<gN4, 256, 0, stream>>>(gbuf, csr_se, offs, dinv, b2, hbuf, N, 0);
    // factorized edge MLP: u = bf16(h2 @ W3a), v = bf16(h2 @ W3b + b3)
    gemm_mfma<<<gM, 256, 0, stream>>>(hbuf, Wt3a, ubuf, nullptr, nullptr, N, 128, 1);
    gemm_mfma<<<gM, 256, 0, stream>>>(hbuf, Wt3b, vbuf, nullptr, b3, N, 128, 1);
    // score per edge: dst-segment order, v in registers, 4-edge ILP
    edge_score_seg<<<(N + 15) / 16, 256, 0, stream>>>(ubuf, vbuf, csr_se, offs,
                                                      W4, b4, outp, N);
}

// Round 11
// 579.961 us; speedup vs baseline: 1.2533x; 1.0042x over previous
//
#include <hip/hip_runtime.h>
#include <math.h>

typedef unsigned short ushort_t;
typedef __attribute__((ext_vector_type(8))) short bf16x8;
typedef __attribute__((ext_vector_type(8))) unsigned short us8;
typedef __attribute__((ext_vector_type(4))) float f32x4;

__device__ __forceinline__ float bf2f(unsigned short u) {
    union { unsigned int i; float f; } x; x.i = ((unsigned int)u) << 16; return x.f;
}
__device__ __forceinline__ unsigned short f2bf(float f) {
    union { float f; unsigned int i; } x; x.f = f;          // round-to-nearest-even
    unsigned int lsb = (x.i >> 16) & 1u;
    return (unsigned short)((x.i + 0x7fffu + lsb) >> 16);
}

// ---------------- edge_index dtype hedge ----------------

__global__ __launch_bounds__(1024) void detect_i64(const int* __restrict__ ei,
                                                   int nwords, int* __restrict__ flag) {
    __shared__ int s_any;
    if (threadIdx.x == 0) s_any = 0;
    __syncthreads();
    int any = 0;
    for (int i = threadIdx.x; 2 * i + 1 < nwords; i += 1024)
        if (ei[2 * i + 1] != 0) any = 1;
    if (any) s_any = 1;           // race-benign
    __syncthreads();
    if (threadIdx.x == 0) flag[0] = (s_any == 0) ? 1 : 0;   // 1 => int64 layout
}

__global__ __launch_bounds__(256) void normalize_idx(const int* __restrict__ ei, int E,
                                                     const int* __restrict__ flag,
                                                     int* __restrict__ s_out,
                                                     int* __restrict__ d_out) {
    int e = blockIdx.x * 256 + threadIdx.x;
    if (e >= E) return;
    if (flag[0]) {                // int64: element i at int32 word 2i (little-endian)
        s_out[e] = ei[2 * e];
        d_out[e] = ei[2 * (E + e)];
    } else {                      // int32 flat [2][E]
        s_out[e] = ei[e];
        d_out[e] = ei[E + e];
    }
}

// ---------------- CSR build (XCD dst-range partitioned) ----------------

__global__ __launch_bounds__(256) void zero_i32(int* __restrict__ p, int n) {
    int i = blockIdx.x * 256 + threadIdx.x;
    if (i < n) p[i] = 0;
}

__global__ __launch_bounds__(256) void count_deg_part(const int* __restrict__ dst,
                                                      int* __restrict__ deg,
                                                      int E, int RB) {
    int xcd = blockIdx.x & 7;
    int e = (blockIdx.x >> 3) * 256 + threadIdx.x;
    if (e >= E) return;
    int d = dst[e];
    if ((unsigned)(d - xcd * RB) < (unsigned)RB) atomicAdd(&deg[d], 1);
}

// single-block exclusive scan over deg -> offs, cursor; also dinv = rsqrt(deg+1)
__global__ __launch_bounds__(1024) void scan_kernel(const int* __restrict__ deg,
                                                    int* __restrict__ offs,
                                                    int* __restrict__ cursor,
                                                    float* __restrict__ dinv, int n) {
    __shared__ int wsum[16];
    __shared__ int s_carry;
    int tid = threadIdx.x, lane = tid & 63, wid = tid >> 6;
    if (tid == 0) s_carry = 0;
    __syncthreads();
    for (int base = 0; base < n; base += 1024) {
        int i = base + tid;
        int v = (i < n) ? deg[i] : 0;
        int x = v;
        #pragma unroll
        for (int d = 1; d < 64; d <<= 1) {
            int y = __shfl_up(x, d, 64);
            if (lane >= d) x += y;
        }
        if (lane == 63) wsum[wid] = x;
        __syncthreads();
        int carry = s_carry;
        __syncthreads();           // everyone read carry before thread0 rewrites
        if (tid == 0) {
            int run = 0;
            #pragma unroll
            for (int w = 0; w < 16; ++w) { int t = wsum[w]; wsum[w] = run; run += t; }
            s_carry = carry + run;
        }
        __syncthreads();
        if (i < n) {
            int excl = carry + wsum[wid] + (x - v);
            offs[i] = excl;
            cursor[i] = excl;
            dinv[i] = rsqrtf((float)(v + 1));   // +1 self loop
        }
        __syncthreads();           // protect wsum before next iteration
    }
    if (tid == 0) offs[n] = s_carry;
}

__global__ __launch_bounds__(256) void fill_csr_part(const int* __restrict__ src,
                                                     const int* __restrict__ dst,
                                                     int* __restrict__ cursor,
                                                     int2* __restrict__ csr_se,
                                                     int E, int RB) {
    int xcd = blockIdx.x & 7;
    int e = (blockIdx.x >> 3) * 256 + threadIdx.x;
    if (e >= E) return;
    int d = dst[e];
    if ((unsigned)(d - xcd * RB) < (unsigned)RB) {
        int pos = atomicAdd(&cursor[d], 1);
        csr_se[pos] = make_int2(src[e], e);
    }
}

// ---------------- weight pre-convert: f32 [K][128] -> bf16 transposed [128][K] ----

__global__ __launch_bounds__(256) void conv_weights(const float* __restrict__ W1,
                                                    const float* __restrict__ W2,
                                                    const float* __restrict__ W3,
                                                    ushort_t* __restrict__ Wt1,
                                                    ushort_t* __restrict__ Wt2,
                                                    ushort_t* __restrict__ Wt3a,
                                                    ushort_t* __restrict__ Wt3b) {
    int t = blockIdx.x * 256 + threadIdx.x;
    if (t < 32768) {                 // W1 [256][128] -> Wt1 [128][256]
        int k = t >> 7, n = t & 127;
        Wt1[n * 256 + k] = f2bf(W1[t]);
    } else if (t < 49152) {          // W2 [128][128]
        int u = t - 32768; int k = u >> 7, n = u & 127;
        Wt2[n * 128 + k] = f2bf(W2[u]);
    } else if (t < 65536) {          // W3a = W3[0:128][:]
        int u = t - 49152; int k = u >> 7, n = u & 127;
        Wt3a[n * 128 + k] = f2bf(W3[u]);
    } else if (t < 81920) {          // W3b = W3[128:256][:]
        int u = t - 65536; int k = u >> 7, n = u & 127;
        Wt3b[n * 128 + k] = f2bf(W3[128 * 128 + u]);
    }
}

// ---------------- bf16 MFMA GEMM, K=256 path (f32 A, LDS-staged; verified) ------
// out[m][n] = scale_m * (sum_k A[m][k] W[k][n]) + bias_n; out bf16.
// Fragment mapping HW-verified (m89/m91): A-frag row=lane&15, k=(lane>>4)*8+i;
// B-frag col=lane&15 same k; C/D col=lane&15, row=(lane>>4)*4+reg.

#define ASTR 40    // ushorts per As row (80B)
#define BSTR 136   // ushorts per Bt row (272B)

__global__ __launch_bounds__(256) void gemm_mfma(const float* __restrict__ A,
                                                 const ushort_t* __restrict__ Wt,
                                                 ushort_t* __restrict__ outp,
                                                 const float* __restrict__ dinv,
                                                 const float* __restrict__ bias,
                                                 int M, int K) {
    __shared__ __attribute__((aligned(16))) ushort_t Bt[128 * BSTR]; // [col][k-kh]
    __shared__ __attribute__((aligned(16))) ushort_t As[64 * ASTR];  // [row][k-k0]
    int tid = threadIdx.x;
    int wave = tid >> 6, lane = tid & 63;
    int l15 = lane & 15, lg = lane >> 4;
    int block_m = blockIdx.x * 64;
    f32x4 acc[8];
    #pragma unroll
    for (int i = 0; i < 8; ++i) acc[i] = (f32x4){0.f, 0.f, 0.f, 0.f};

    for (int kh = 0; kh < K; kh += 128) {
        #pragma unroll
        for (int i = 0; i < 16; ++i) {
            int u = i * 256 + tid;             // ushort4 unit
            int col = u >> 5;
            int kq = (u & 31) * 4;
            ushort4 w = *(const ushort4*)(&Wt[(size_t)col * K + kh + kq]);
            *(ushort4*)(&Bt[col * BSTR + kq]) = w;
        }
        for (int k0 = kh; k0 < kh + 128; k0 += 32) {
            #pragma unroll
            for (int rep = 0; rep < 2; ++rep) {
                int unit = rep * 256 + tid;
                int r = unit >> 3;             // 0..63
                int kc = (unit & 7) * 4;       // 0..28
                int gr = block_m + r;
                int grc = gr < M ? gr : M - 1;
                float4 v = *(const float4*)(&A[(size_t)grc * K + k0 + kc]);
                if (gr >= M) v = make_float4(0.f, 0.f, 0.f, 0.f);
                ushort4 p;
                p.x = f2bf(v.x); p.y = f2bf(v.y); p.z = f2bf(v.z); p.w = f2bf(v.w);
                *(ushort4*)(&As[r * ASTR + kc]) = p;
            }
            __syncthreads();
            bf16x8 af = *(const bf16x8*)(&As[(wave * 16 + l15) * ASTR + lg * 8]);
            #pragma unroll
            for (int nf = 0; nf < 8; ++nf) {
                bf16x8 bf = *(const bf16x8*)(&Bt[(nf * 16 + l15) * BSTR +
                                                 (k0 - kh) + lg * 8]);
                acc[nf] = __builtin_amdgcn_mfma_f32_16x16x32_bf16(af, bf, acc[nf],
                                                                  0, 0, 0);
            }
            __syncthreads();
        }
    }
    int orow = block_m + wave * 16 + lg * 4;
    #pragma unroll
    for (int nf = 0; nf < 8; ++nf) {
        int col = nf * 16 + l15;
        float bb = bias ? bias[col] : 0.f;
        #pragma unroll
        for (int j = 0; j < 4; ++j) {
            int m = orow + j;
            if (m < M) {
                float s = dinv ? dinv[m] : 1.f;
                outp[(size_t)m * 128 + col] = f2bf(acc[nf][j] * s + bb);
            }
        }
    }
}

// ---------------- bf16 MFMA GEMM, K=128 reg-B path (bf16 A, no LDS, no syncs) ---
// Per wave: full B (8 col-frags x 4 k-frags = 128 VGPR) loaded once; grid-stride
// over 16-row m-tiles; A-frags loaded straight from global bf16 (lane quarter
// covers one 64B line per row). Fragment values byte-identical to gemm_mfma.

__global__ __launch_bounds__(256) void gemm_regB(const ushort_t* __restrict__ A,
                                                 const ushort_t* __restrict__ Wt,
                                                 ushort_t* __restrict__ outp,
                                                 const float* __restrict__ dinv,
                                                 const float* __restrict__ bias,
                                                 int M) {
    int tid = threadIdx.x;
    int wave = tid >> 6, lane = tid & 63;
    int l15 = lane & 15, lg = lane >> 4;
    bf16x8 Bf[8][4];
    #pragma unroll
    for (int nf = 0; nf < 8; ++nf)
        #pragma unroll
        for (int ks = 0; ks < 4; ++ks)
            Bf[nf][ks] = *(const bf16x8*)(&Wt[(size_t)(nf * 16 + l15) * 128 +
                                              ks * 32 + lg * 8]);
    float bv[8];
    #pragma unroll
    for (int nf = 0; nf < 8; ++nf)
        bv[nf] = bias ? bias[nf * 16 + l15] : 0.f;

    int nt = (M + 15) >> 4;
    for (int tile = blockIdx.x * 4 + wave; tile < nt; tile += gridDim.x * 4) {
        int r = tile * 16 + l15;
        const ushort_t* Ar = A + (size_t)(r < M ? r : M - 1) * 128;
        bf16x8 af0 = *(const bf16x8*)(Ar + 0 * 32 + lg * 8);
        bf16x8 af1 = *(const bf16x8*)(Ar + 1 * 32 + lg * 8);
        bf16x8 af2 = *(const bf16x8*)(Ar + 2 * 32 + lg * 8);
        bf16x8 af3 = *(const bf16x8*)(Ar + 3 * 32 + lg * 8);
        f32x4 acc[8];
        #pragma unroll
        for (int i = 0; i < 8; ++i) acc[i] = (f32x4){0.f, 0.f, 0.f, 0.f};
        #pragma unroll
        for (int nf = 0; nf < 8; ++nf) {
            acc[nf] = __builtin_amdgcn_mfma_f32_16x16x32_bf16(af0, Bf[nf][0], acc[nf], 0, 0, 0);
            acc[nf] = __builtin_amdgcn_mfma_f32_16x16x32_bf16(af1, Bf[nf][1], acc[nf], 0, 0, 0);
            acc[nf] = __builtin_amdgcn_mfma_f32_16x16x32_bf16(af2, Bf[nf][2], acc[nf], 0, 0, 0);
            acc[nf] = __builtin_amdgcn_mfma_f32_16x16x32_bf16(af3, Bf[nf][3], acc[nf], 0, 0, 0);
        }
        int orow = tile * 16 + lg * 4;
        #pragma unroll
        for (int nf = 0; nf < 8; ++nf) {
            int col = nf * 16 + l15;
            #pragma unroll
            for (int j = 0; j < 4; ++j) {
                int m = orow + j;
                if (m < M) {
                    float s = dinv ? dinv[m] : 1.f;
                    outp[(size_t)m * 128 + col] = f2bf(acc[nf][j] * s + bv[nf]);
                }
            }
        }
    }
}

// ---------------- pull aggregation: 8 neighbors in flight, bf16 output ----------
// out[n] = act( dinv[n]*(g[n] + sum_{i in CSR[n]} g[src_i]) + bias )

__global__ __launch_bounds__(256) void pull_agg(const ushort_t* __restrict__ g,
                                                const int2* __restrict__ csr_se,
                                                const int* __restrict__ offs,
                                                const float* __restrict__ dinv,
                                                const float* __restrict__ bias,
                                                ushort_t* __restrict__ out,
                                                int n_nodes, int do_relu) {
    int tid = threadIdx.x;
    int wid = tid >> 6, lane = tid & 63;
    int q = lane >> 4, c = lane & 15;
    int node = blockIdx.x * 4 + wid;
    if (node >= n_nodes) return;
    int beg = offs[node], end = offs[node + 1];
    float acc[8] = {};
    int i = beg;
    for (; i + 8 <= end; i += 8) {
        int s1 = csr_se[i + q].x;
        int s2 = csr_se[i + 4 + q].x;
        us8 r1 = *(const us8*)(g + (size_t)s1 * 128 + c * 8);
        us8 r2 = *(const us8*)(g + (size_t)s2 * 128 + c * 8);
        acc[0] += bf2f(r1[0]); acc[1] += bf2f(r1[1]);
        acc[2] += bf2f(r1[2]); acc[3] += bf2f(r1[3]);
        acc[4] += bf2f(r1[4]); acc[5] += bf2f(r1[5]);
        acc[6] += bf2f(r1[6]); acc[7] += bf2f(r1[7]);
        acc[0] += bf2f(r2[0]); acc[1] += bf2f(r2[1]);
        acc[2] += bf2f(r2[2]); acc[3] += bf2f(r2[3]);
        acc[4] += bf2f(r2[4]); acc[5] += bf2f(r2[5]);
        acc[6] += bf2f(r2[6]); acc[7] += bf2f(r2[7]);
    }
    for (; i < end; i += 4) {
        int j = i + q;
        int sidx = (j < end) ? csr_se[j].x : n_nodes;   // zero row when invalid
        us8 r = *(const us8*)(g + (size_t)sidx * 128 + c * 8);
        acc[0] += bf2f(r[0]); acc[1] += bf2f(r[1]);
        acc[2] += bf2f(r[2]); acc[3] += bf2f(r[3]);
        acc[4] += bf2f(r[4]); acc[5] += bf2f(r[5]);
        acc[6] += bf2f(r[6]); acc[7] += bf2f(r[7]);
    }
    #pragma unroll
    for (int k = 0; k < 8; ++k) {
        acc[k] += __shfl_xor(acc[k], 16, 64);
        acc[k] += __shfl_xor(acc[k], 32, 64);
    }
    // self-loop row
    us8 sr = *(const us8*)(g + (size_t)node * 128 + c * 8);
    float s = dinv[node];
    float4 ba = *(const float4*)(&bias[c * 8]);
    float4 bb = *(const float4*)(&bias[c * 8 + 4]);
    float o[8];
    o[0] = (acc[0] + bf2f(sr[0])) * s + ba.x;
    o[1] = (acc[1] + bf2f(sr[1])) * s + ba.y;
    o[2] = (acc[2] + bf2f(sr[2])) * s + ba.z;
    o[3] = (acc[3] + bf2f(sr[3])) * s + ba.w;
    o[4] = (acc[4] + bf2f(sr[4])) * s + bb.x;
    o[5] = (acc[5] + bf2f(sr[5])) * s + bb.y;
    o[6] = (acc[6] + bf2f(sr[6])) * s + bb.z;
    o[7] = (acc[7] + bf2f(sr[7])) * s + bb.w;
    if (do_relu) {
        #pragma unroll
        for (int k = 0; k < 8; ++k) o[k] = fmaxf(o[k], 0.f);
    }
    if (q == 0) {
        us8 w;
        #pragma unroll
        for (int k = 0; k < 8; ++k) w[k] = f2bf(o[k]);
        *(us8*)(out + (size_t)node * 128 + c * 8) = w;
    }
}

// ---------------- edge scorer: dst-segment form, 4-edge ILP ----------------
// score[eid] = sigmoid( sum_j relu(u[s][j] + v[d][j]) * W4[j] + b4 )

__device__ __forceinline__ float edot8(const us8& uu, const float* vr,
                                       const float4& wa, const float4& wb) {
    float ps;
    ps  = fmaxf(bf2f(uu[0]) + vr[0], 0.f) * wa.x;
    ps += fmaxf(bf2f(uu[1]) + vr[1], 0.f) * wa.y;
    ps += fmaxf(bf2f(uu[2]) + vr[2], 0.f) * wa.z;
    ps += fmaxf(bf2f(uu[3]) + vr[3], 0.f) * wa.w;
    ps += fmaxf(bf2f(uu[4]) + vr[4], 0.f) * wb.x;
    ps += fmaxf(bf2f(uu[5]) + vr[5], 0.f) * wb.y;
    ps += fmaxf(bf2f(uu[6]) + vr[6], 0.f) * wb.z;
    ps += fmaxf(bf2f(uu[7]) + vr[7], 0.f) * wb.w;
    ps += __shfl_xor(ps, 8, 64);
    ps += __shfl_xor(ps, 4, 64);
    ps += __shfl_xor(ps, 2, 64);
    ps += __shfl_xor(ps, 1, 64);
    return ps;
}

__global__ __launch_bounds__(256) void edge_score_seg(const ushort_t* __restrict__ u,
                                                      const ushort_t* __restrict__ v,
                                                      const int2* __restrict__ csr_se,
                                                      const int* __restrict__ offs,
                                                      const float* __restrict__ W4,
                                                      const float* __restrict__ b4,
                                                      float* __restrict__ out,
                                                      int n_nodes) {
    int tid = threadIdx.x;
    int grp = tid >> 4, c = tid & 15;
    int node = blockIdx.x * 16 + grp;
    if (node >= n_nodes) return;
    int beg = offs[node], end = offs[node + 1];
    if (beg == end) return;
    us8 vv = *(const us8*)(v + (size_t)node * 128 + c * 8);
    float vr[8];
    #pragma unroll
    for (int k = 0; k < 8; ++k) vr[k] = bf2f(vv[k]);
    float4 wa = *(const float4*)(&W4[c * 8]);
    float4 wb = *(const float4*)(&W4[c * 8 + 4]);
    float b4v = b4[0];
    int p = beg;
    for (; p + 4 <= end; p += 4) {
        int2 se0 = csr_se[p];
        int2 se1 = csr_se[p + 1];
        int2 se2 = csr_se[p + 2];
        int2 se3 = csr_se[p + 3];
        us8 u0 = *(const us8*)(u + (size_t)se0.x * 128 + c * 8);
        us8 u1 = *(const us8*)(u + (size_t)se1.x * 128 + c * 8);
        us8 u2 = *(const us8*)(u + (size_t)se2.x * 128 + c * 8);
        us8 u3 = *(const us8*)(u + (size_t)se3.x * 128 + c * 8);
        float p0 = edot8(u0, vr, wa, wb);
        float p1 = edot8(u1, vr, wa, wb);
        float p2 = edot8(u2, vr, wa, wb);
        float p3 = edot8(u3, vr, wa, wb);
        if (c == 0) {
            out[se0.y] = 1.f / (1.f + expf(-(p0 + b4v)));
            out[se1.y] = 1.f / (1.f + expf(-(p1 + b4v)));
            out[se2.y] = 1.f / (1.f + expf(-(p2 + b4v)));
            out[se3.y] = 1.f / (1.f + expf(-(p3 + b4v)));
        }
    }
    for (; p < end; ++p) {
        int2 se = csr_se[p];
        us8 uu = *(const us8*)(u + (size_t)se.x * 128 + c * 8);
        float ps = edot8(uu, vr, wa, wb);
        if (c == 0)
            out[se.y] = 1.f / (1.f + expf(-(ps + b4v)));
    }
}

// ---------------- launcher ----------------

extern "C" void kernel_launch(void* const* d_in, const int* in_sizes, int n_in,
                              void* d_out, int out_size, void* d_ws, size_t ws_size,
                              hipStream_t stream) {
    const float* x  = (const float*)d_in[0];
    const int*   ei = (const int*)d_in[1];
    const float* W1 = (const float*)d_in[2];
    const float* b1 = (const float*)d_in[3];
    const float* W2 = (const float*)d_in[4];
    const float* b2 = (const float*)d_in[5];
    const float* W3 = (const float*)d_in[6];
    const float* b3 = (const float*)d_in[7];
    const float* W4 = (const float*)d_in[8];
    const float* b4 = (const float*)d_in[9];

    int N = in_sizes[0] / 256;      // 50000
    int E = in_sizes[1] / 2;        // 1.6M

    char* ws = (char*)d_ws;
    size_t off = 0;
    auto alloc = [&](size_t bytes) -> void* {
        void* p = ws + off;
        off += (bytes + 255) & ~(size_t)255;
        return p;
    };
    int*      flag    = (int*)     alloc(256);
    int*      srcn    = (int*)     alloc((size_t)E * 4);
    int*      dstn    = (int*)     alloc((size_t)E * 4);
    int*      deg     = (int*)     alloc((size_t)N * 4);
    int*      offs    = (int*)     alloc((size_t)(N + 1) * 4);
    int*      cursor  = (int*)     alloc((size_t)N * 4);
    float*    dinv    = (float*)   alloc((size_t)N * 4);
    int2*     csr_se  = (int2*)    alloc((size_t)E * 8);
    ushort_t* gbuf    = (ushort_t*)alloc((size_t)(N + 1) * 128 * 2); // + zero row
    ushort_t* ubuf    = (ushort_t*)alloc((size_t)N * 128 * 2);       // bf16 u table
    ushort_t* vbuf    = (ushort_t*)alloc((size_t)N * 128 * 2);       // bf16 v table
    ushort_t* hbuf    = (ushort_t*)alloc((size_t)N * 128 * 2);       // bf16 h
    ushort_t* Wt1     = (ushort_t*)alloc(128 * 256 * 2);
    ushort_t* Wt2     = (ushort_t*)alloc(128 * 128 * 2);
    ushort_t* Wt3a    = (ushort_t*)alloc(128 * 128 * 2);
    ushort_t* Wt3b    = (ushort_t*)alloc(128 * 128 * 2);
    (void)ws_size; (void)n_in; (void)out_size;

    float* outp = (float*)d_out;
    int gE = (E + 255) / 256;
    int gN4 = (N + 3) / 4;
    int RB = (N + 7) / 8;           // dst-range per XCD

    // dtype hedge + index normalization
    int nwords = (2 * E < 4096) ? 2 * E : 4096;
    detect_i64<<<1, 1024, 0, stream>>>(ei, nwords, flag);
    normalize_idx<<<gE, 256, 0, stream>>>(ei, E, flag, srcn, dstn);
    conv_weights<<<320, 256, 0, stream>>>(W1, W2, W3, Wt1, Wt2, Wt3a, Wt3b);

    // CSR (by dst) + dinv, XCD dst-range partitioned; zero the padding row of gbuf
    zero_i32<<<(N + 255) / 256, 256, 0, stream>>>(deg, N);
    zero_i32<<<1, 256, 0, stream>>>((int*)(gbuf + (size_t)N * 128), 64);
    count_deg_part<<<gE * 8, 256, 0, stream>>>(dstn, deg, E, RB);
    scan_kernel<<<1, 1024, 0, stream>>>(deg, offs, cursor, dinv, N);
    fill_csr_part<<<gE * 8, 256, 0, stream>>>(srcn, dstn, cursor, csr_se, E, RB);

    int gM = (N + 63) / 64;
    // layer 1: g1 = bf16(dinv * (x @ W1));  h1 = bf16(relu(dinv*(sum g1) + b1))
    gemm_mfma<<<gM, 256, 0, stream>>>(x, Wt1, gbuf, dinv, nullptr, N, 256);
    pull_agg<<<gN4, 256, 0, stream>>>(gbuf, csr_se, offs, dinv, b1, hbuf, N, 1);
    // layer 2: g2 = bf16(dinv * (h1 @ W2)); h2 = bf16(dinv*(sum g2) + b2)
    gemm_regB<<<512, 256, 0, stream>>>(hbuf, Wt2, gbuf, dinv, nullptr, N);
    pull_agg<<<gN4, 256, 0, stream>>>(gbuf, csr_se, offs, dinv, b2, hbuf, N, 0);
    // factorized edge MLP: u = bf16(h2 @ W3a), v = bf16(h2 @ W3b + b3)
    gemm_regB<<<512, 256, 0, stream>>>(hbuf, Wt3a, ubuf, nullptr, nullptr, N);
    gemm_regB<<<512, 256, 0, stream>>>(hbuf, Wt3b, vbuf, nullptr, b3, N);
    // score per edge: dst-segment order, v in registers, 4-edge ILP
    edge_score_seg<<<(N + 15) / 16, 256, 0, stream>>>(ubuf, vbuf, csr_se, offs,
                                                      W4, b4, outp, N);
}

// Round 12
// 531.056 us; speedup vs baseline: 1.3687x; 1.0921x over previous
//
#include <hip/hip_runtime.h>
#include <math.h>

typedef unsigned short ushort_t;
typedef __attribute__((ext_vector_type(8))) short bf16x8;
typedef __attribute__((ext_vector_type(8))) unsigned short us8;
typedef __attribute__((ext_vector_type(4))) float f32x4;

__device__ __forceinline__ float bf2f(unsigned short u) {
    union { unsigned int i; float f; } x; x.i = ((unsigned int)u) << 16; return x.f;
}
__device__ __forceinline__ unsigned short f2bf(float f) {
    union { float f; unsigned int i; } x; x.f = f;          // round-to-nearest-even
    unsigned int lsb = (x.i >> 16) & 1u;
    return (unsigned short)((x.i + 0x7fffu + lsb) >> 16);
}

// ---------------- edge_index dtype hedge ----------------

__global__ __launch_bounds__(1024) void detect_i64(const int* __restrict__ ei,
                                                   int nwords, int* __restrict__ flag) {
    __shared__ int s_any;
    if (threadIdx.x == 0) s_any = 0;
    __syncthreads();
    int any = 0;
    for (int i = threadIdx.x; 2 * i + 1 < nwords; i += 1024)
        if (ei[2 * i + 1] != 0) any = 1;
    if (any) s_any = 1;           // race-benign
    __syncthreads();
    if (threadIdx.x == 0) flag[0] = (s_any == 0) ? 1 : 0;   // 1 => int64 layout
}

__global__ __launch_bounds__(256) void normalize_idx(const int* __restrict__ ei, int E,
                                                     const int* __restrict__ flag,
                                                     int* __restrict__ s_out,
                                                     int* __restrict__ d_out) {
    int e = blockIdx.x * 256 + threadIdx.x;
    if (e >= E) return;
    if (flag[0]) {                // int64: element i at int32 word 2i (little-endian)
        s_out[e] = ei[2 * e];
        d_out[e] = ei[2 * (E + e)];
    } else {                      // int32 flat [2][E]
        s_out[e] = ei[e];
        d_out[e] = ei[E + e];
    }
}

// ---------------- CSR build (XCD dst-range partitioned) ----------------

__global__ __launch_bounds__(256) void zero_i32(int* __restrict__ p, int n) {
    int i = blockIdx.x * 256 + threadIdx.x;
    if (i < n) p[i] = 0;
}

__global__ __launch_bounds__(256) void count_deg_part(const int* __restrict__ dst,
                                                      int* __restrict__ deg,
                                                      int E, int RB) {
    int xcd = blockIdx.x & 7;
    int e = (blockIdx.x >> 3) * 256 + threadIdx.x;
    if (e >= E) return;
    int d = dst[e];
    if ((unsigned)(d - xcd * RB) < (unsigned)RB) atomicAdd(&deg[d], 1);
}

// ---------------- parallel exclusive scan (3 passes) ----------------
// A: per-block (256 elems) exclusive scan + block total
__global__ __launch_bounds__(256) void scan_blk(const int* __restrict__ deg,
                                                int* __restrict__ excl,
                                                int* __restrict__ bsum, int n) {
    __shared__ int wsum[4];
    int i = blockIdx.x * 256 + threadIdx.x;
    int lane = threadIdx.x & 63, wid = threadIdx.x >> 6;
    int v = (i < n) ? deg[i] : 0;
    int x = v;
    #pragma unroll
    for (int d = 1; d < 64; d <<= 1) {
        int y = __shfl_up(x, d, 64);
        if (lane >= d) x += y;
    }
    if (lane == 63) wsum[wid] = x;
    __syncthreads();
    if (threadIdx.x == 0) {
        int run = 0;
        #pragma unroll
        for (int w = 0; w < 4; ++w) { int t = wsum[w]; wsum[w] = run; run += t; }
        bsum[blockIdx.x] = run;
    }
    __syncthreads();
    if (i < n) excl[i] = wsum[wid] + (x - v);
}

// B: single block scans bsum[0..nb) in place (exclusive); bsum[nb] = total
__global__ __launch_bounds__(256) void scan_top(int* __restrict__ bsum, int nb) {
    __shared__ int wsum[4];
    int tid = threadIdx.x, lane = tid & 63, wid = tid >> 6;
    int v = (tid < nb) ? bsum[tid] : 0;
    int x = v;
    #pragma unroll
    for (int d = 1; d < 64; d <<= 1) {
        int y = __shfl_up(x, d, 64);
        if (lane >= d) x += y;
    }
    if (lane == 63) wsum[wid] = x;
    __syncthreads();
    if (tid == 0) {
        int run = 0;
        #pragma unroll
        for (int w = 0; w < 4; ++w) { int t = wsum[w]; wsum[w] = run; run += t; }
        bsum[nb] = run;                     // total
    }
    __syncthreads();
    if (tid < nb) bsum[tid] = wsum[wid] + (x - v);
}

// C: finalize offs/cursor/dinv
__global__ __launch_bounds__(256) void scan_fin(const int* __restrict__ deg,
                                                const int* __restrict__ excl,
                                                const int* __restrict__ bsum,
                                                int* __restrict__ offs,
                                                int* __restrict__ cursor,
                                                float* __restrict__ dinv,
                                                int n, int nb) {
    int i = blockIdx.x * 256 + threadIdx.x;
    if (i < n) {
        int e = excl[i] + bsum[blockIdx.x];
        offs[i] = e;
        cursor[i] = e;
        dinv[i] = rsqrtf((float)(deg[i] + 1));   // +1 self loop
    }
    if (i == 0) offs[n] = bsum[nb];
}

__global__ __launch_bounds__(256) void fill_csr_part(const int* __restrict__ src,
                                                     const int* __restrict__ dst,
                                                     int* __restrict__ cursor,
                                                     int2* __restrict__ csr_se,
                                                     int E, int RB) {
    int xcd = blockIdx.x & 7;
    int e = (blockIdx.x >> 3) * 256 + threadIdx.x;
    if (e >= E) return;
    int d = dst[e];
    if ((unsigned)(d - xcd * RB) < (unsigned)RB) {
        int pos = atomicAdd(&cursor[d], 1);
        csr_se[pos] = make_int2(src[e], e);
    }
}

// ---------------- weight pre-convert: f32 [K][128] -> bf16 transposed [128][K] ----

__global__ __launch_bounds__(256) void conv_weights(const float* __restrict__ W1,
                                                    const float* __restrict__ W2,
                                                    const float* __restrict__ W3,
                                                    ushort_t* __restrict__ Wt1,
                                                    ushort_t* __restrict__ Wt2,
                                                    ushort_t* __restrict__ Wt3a,
                                                    ushort_t* __restrict__ Wt3b) {
    int t = blockIdx.x * 256 + threadIdx.x;
    if (t < 32768) {                 // W1 [256][128] -> Wt1 [128][256]
        int k = t >> 7, n = t & 127;
        Wt1[n * 256 + k] = f2bf(W1[t]);
    } else if (t < 49152) {          // W2 [128][128]
        int u = t - 32768; int k = u >> 7, n = u & 127;
        Wt2[n * 128 + k] = f2bf(W2[u]);
    } else if (t < 65536) {          // W3a = W3[0:128][:]
        int u = t - 49152; int k = u >> 7, n = u & 127;
        Wt3a[n * 128 + k] = f2bf(W3[u]);
    } else if (t < 81920) {          // W3b = W3[128:256][:]
        int u = t - 65536; int k = u >> 7, n = u & 127;
        Wt3b[n * 128 + k] = f2bf(W3[128 * 128 + u]);
    }
}

// ---------------- bf16 MFMA GEMM, K=256 path (f32 A, LDS-staged; verified) ------
// Fragment mapping HW-verified (m89/m91): A-frag row=lane&15, k=(lane>>4)*8+i;
// B-frag col=lane&15 same k; C/D col=lane&15, row=(lane>>4)*4+reg.

#define ASTR 40    // ushorts per As row (80B)
#define BSTR 136   // ushorts per Bt row (272B)

__global__ __launch_bounds__(256) void gemm_mfma(const float* __restrict__ A,
                                                 const ushort_t* __restrict__ Wt,
                                                 ushort_t* __restrict__ outp,
                                                 const float* __restrict__ dinv,
                                                 const float* __restrict__ bias,
                                                 int M, int K) {
    __shared__ __attribute__((aligned(16))) ushort_t Bt[128 * BSTR]; // [col][k-kh]
    __shared__ __attribute__((aligned(16))) ushort_t As[64 * ASTR];  // [row][k-k0]
    int tid = threadIdx.x;
    int wave = tid >> 6, lane = tid & 63;
    int l15 = lane & 15, lg = lane >> 4;
    int block_m = blockIdx.x * 64;
    f32x4 acc[8];
    #pragma unroll
    for (int i = 0; i < 8; ++i) acc[i] = (f32x4){0.f, 0.f, 0.f, 0.f};

    for (int kh = 0; kh < K; kh += 128) {
        #pragma unroll
        for (int i = 0; i < 16; ++i) {
            int u = i * 256 + tid;             // ushort4 unit
            int col = u >> 5;
            int kq = (u & 31) * 4;
            ushort4 w = *(const ushort4*)(&Wt[(size_t)col * K + kh + kq]);
            *(ushort4*)(&Bt[col * BSTR + kq]) = w;
        }
        for (int k0 = kh; k0 < kh + 128; k0 += 32) {
            #pragma unroll
            for (int rep = 0; rep < 2; ++rep) {
                int unit = rep * 256 + tid;
                int r = unit >> 3;             // 0..63
                int kc = (unit & 7) * 4;       // 0..28
                int gr = block_m + r;
                int grc = gr < M ? gr : M - 1;
                float4 v = *(const float4*)(&A[(size_t)grc * K + k0 + kc]);
                if (gr >= M) v = make_float4(0.f, 0.f, 0.f, 0.f);
                ushort4 p;
                p.x = f2bf(v.x); p.y = f2bf(v.y); p.z = f2bf(v.z); p.w = f2bf(v.w);
                *(ushort4*)(&As[r * ASTR + kc]) = p;
            }
            __syncthreads();
            bf16x8 af = *(const bf16x8*)(&As[(wave * 16 + l15) * ASTR + lg * 8]);
            #pragma unroll
            for (int nf = 0; nf < 8; ++nf) {
                bf16x8 bf = *(const bf16x8*)(&Bt[(nf * 16 + l15) * BSTR +
                                                 (k0 - kh) + lg * 8]);
                acc[nf] = __builtin_amdgcn_mfma_f32_16x16x32_bf16(af, bf, acc[nf],
                                                                  0, 0, 0);
            }
            __syncthreads();
        }
    }
    int orow = block_m + wave * 16 + lg * 4;
    #pragma unroll
    for (int nf = 0; nf < 8; ++nf) {
        int col = nf * 16 + l15;
        float bb = bias ? bias[col] : 0.f;
        #pragma unroll
        for (int j = 0; j < 4; ++j) {
            int m = orow + j;
            if (m < M) {
                float s = dinv ? dinv[m] : 1.f;
                outp[(size_t)m * 128 + col] = f2bf(acc[nf][j] * s + bb);
            }
        }
    }
}

// ---------------- bf16 MFMA GEMM, K=128 reg-B path (bf16 A, no LDS, no syncs) ---

__global__ __launch_bounds__(256) void gemm_regB(const ushort_t* __restrict__ A,
                                                 const ushort_t* __restrict__ Wt,
                                                 ushort_t* __restrict__ outp,
                                                 const float* __restrict__ dinv,
                                                 const float* __restrict__ bias,
                                                 int M) {
    int tid = threadIdx.x;
    int wave = tid >> 6, lane = tid & 63;
    int l15 = lane & 15, lg = lane >> 4;
    bf16x8 Bf[8][4];
    #pragma unroll
    for (int nf = 0; nf < 8; ++nf)
        #pragma unroll
        for (int ks = 0; ks < 4; ++ks)
            Bf[nf][ks] = *(const bf16x8*)(&Wt[(size_t)(nf * 16 + l15) * 128 +
                                              ks * 32 + lg * 8]);
    float bv[8];
    #pragma unroll
    for (int nf = 0; nf < 8; ++nf)
        bv[nf] = bias ? bias[nf * 16 + l15] : 0.f;

    int nt = (M + 15) >> 4;
    for (int tile = blockIdx.x * 4 + wave; tile < nt; tile += gridDim.x * 4) {
        int r = tile * 16 + l15;
        const ushort_t* Ar = A + (size_t)(r < M ? r : M - 1) * 128;
        bf16x8 af0 = *(const bf16x8*)(Ar + 0 * 32 + lg * 8);
        bf16x8 af1 = *(const bf16x8*)(Ar + 1 * 32 + lg * 8);
        bf16x8 af2 = *(const bf16x8*)(Ar + 2 * 32 + lg * 8);
        bf16x8 af3 = *(const bf16x8*)(Ar + 3 * 32 + lg * 8);
        f32x4 acc[8];
        #pragma unroll
        for (int i = 0; i < 8; ++i) acc[i] = (f32x4){0.f, 0.f, 0.f, 0.f};
        #pragma unroll
        for (int nf = 0; nf < 8; ++nf) {
            acc[nf] = __builtin_amdgcn_mfma_f32_16x16x32_bf16(af0, Bf[nf][0], acc[nf], 0, 0, 0);
            acc[nf] = __builtin_amdgcn_mfma_f32_16x16x32_bf16(af1, Bf[nf][1], acc[nf], 0, 0, 0);
            acc[nf] = __builtin_amdgcn_mfma_f32_16x16x32_bf16(af2, Bf[nf][2], acc[nf], 0, 0, 0);
            acc[nf] = __builtin_amdgcn_mfma_f32_16x16x32_bf16(af3, Bf[nf][3], acc[nf], 0, 0, 0);
        }
        int orow = tile * 16 + lg * 4;
        #pragma unroll
        for (int nf = 0; nf < 8; ++nf) {
            int col = nf * 16 + l15;
            #pragma unroll
            for (int j = 0; j < 4; ++j) {
                int m = orow + j;
                if (m < M) {
                    float s = dinv ? dinv[m] : 1.f;
                    outp[(size_t)m * 128 + col] = f2bf(acc[nf][j] * s + bv[nf]);
                }
            }
        }
    }
}

// ---------------- pull aggregation: 16 neighbors in flight, bf16 output ----------

__device__ __forceinline__ void acc8(float* acc, const us8& r) {
    acc[0] += bf2f(r[0]); acc[1] += bf2f(r[1]);
    acc[2] += bf2f(r[2]); acc[3] += bf2f(r[3]);
    acc[4] += bf2f(r[4]); acc[5] += bf2f(r[5]);
    acc[6] += bf2f(r[6]); acc[7] += bf2f(r[7]);
}

__global__ __launch_bounds__(256) void pull_agg(const ushort_t* __restrict__ g,
                                                const int2* __restrict__ csr_se,
                                                const int* __restrict__ offs,
                                                const float* __restrict__ dinv,
                                                const float* __restrict__ bias,
                                                ushort_t* __restrict__ out,
                                                int n_nodes, int do_relu) {
    int tid = threadIdx.x;
    int wid = tid >> 6, lane = tid & 63;
    int q = lane >> 4, c = lane & 15;
    int node = blockIdx.x * 4 + wid;
    if (node >= n_nodes) return;
    int beg = offs[node], end = offs[node + 1];
    float acc[8] = {};
    int i = beg;
    for (; i + 16 <= end; i += 16) {
        int sA = csr_se[i + q].x;
        int sB = csr_se[i + 4 + q].x;
        int sC = csr_se[i + 8 + q].x;
        int sD = csr_se[i + 12 + q].x;
        us8 rA = *(const us8*)(g + (size_t)sA * 128 + c * 8);
        us8 rB = *(const us8*)(g + (size_t)sB * 128 + c * 8);
        us8 rC = *(const us8*)(g + (size_t)sC * 128 + c * 8);
        us8 rD = *(const us8*)(g + (size_t)sD * 128 + c * 8);
        acc8(acc, rA); acc8(acc, rB); acc8(acc, rC); acc8(acc, rD);
    }
    for (; i < end; i += 4) {
        int j = i + q;
        int sidx = (j < end) ? csr_se[j].x : n_nodes;   // zero row when invalid
        us8 r = *(const us8*)(g + (size_t)sidx * 128 + c * 8);
        acc8(acc, r);
    }
    #pragma unroll
    for (int k = 0; k < 8; ++k) {
        acc[k] += __shfl_xor(acc[k], 16, 64);
        acc[k] += __shfl_xor(acc[k], 32, 64);
    }
    // self-loop row
    us8 sr = *(const us8*)(g + (size_t)node * 128 + c * 8);
    float s = dinv[node];
    float4 ba = *(const float4*)(&bias[c * 8]);
    float4 bb = *(const float4*)(&bias[c * 8 + 4]);
    float o[8];
    o[0] = (acc[0] + bf2f(sr[0])) * s + ba.x;
    o[1] = (acc[1] + bf2f(sr[1])) * s + ba.y;
    o[2] = (acc[2] + bf2f(sr[2])) * s + ba.z;
    o[3] = (acc[3] + bf2f(sr[3])) * s + ba.w;
    o[4] = (acc[4] + bf2f(sr[4])) * s + bb.x;
    o[5] = (acc[5] + bf2f(sr[5])) * s + bb.y;
    o[6] = (acc[6] + bf2f(sr[6])) * s + bb.z;
    o[7] = (acc[7] + bf2f(sr[7])) * s + bb.w;
    if (do_relu) {
        #pragma unroll
        for (int k = 0; k < 8; ++k) o[k] = fmaxf(o[k], 0.f);
    }
    if (q == 0) {
        us8 w;
        #pragma unroll
        for (int k = 0; k < 8; ++k) w[k] = f2bf(o[k]);
        *(us8*)(out + (size_t)node * 128 + c * 8) = w;
    }
}

// ---------------- edge scorer: dst-segment form, 8-edge ILP ----------------
// score[eid] = sigmoid( sum_j relu(u[s][j] + v[d][j]) * W4[j] + b4 )

__device__ __forceinline__ float edot8(const us8& uu, const float* vr,
                                       const float4& wa, const float4& wb) {
    float ps;
    ps  = fmaxf(bf2f(uu[0]) + vr[0], 0.f) * wa.x;
    ps += fmaxf(bf2f(uu[1]) + vr[1], 0.f) * wa.y;
    ps += fmaxf(bf2f(uu[2]) + vr[2], 0.f) * wa.z;
    ps += fmaxf(bf2f(uu[3]) + vr[3], 0.f) * wa.w;
    ps += fmaxf(bf2f(uu[4]) + vr[4], 0.f) * wb.x;
    ps += fmaxf(bf2f(uu[5]) + vr[5], 0.f) * wb.y;
    ps += fmaxf(bf2f(uu[6]) + vr[6], 0.f) * wb.z;
    ps += fmaxf(bf2f(uu[7]) + vr[7], 0.f) * wb.w;
    ps += __shfl_xor(ps, 8, 64);
    ps += __shfl_xor(ps, 4, 64);
    ps += __shfl_xor(ps, 2, 64);
    ps += __shfl_xor(ps, 1, 64);
    return ps;
}

__global__ __launch_bounds__(256) void edge_score_seg(const ushort_t* __restrict__ u,
                                                      const ushort_t* __restrict__ v,
                                                      const int2* __restrict__ csr_se,
                                                      const int* __restrict__ offs,
                                                      const float* __restrict__ W4,
                                                      const float* __restrict__ b4,
                                                      float* __restrict__ out,
                                                      int n_nodes) {
    int tid = threadIdx.x;
    int grp = tid >> 4, c = tid & 15;
    int node = blockIdx.x * 16 + grp;
    if (node >= n_nodes) return;
    int beg = offs[node], end = offs[node + 1];
    if (beg == end) return;
    us8 vv = *(const us8*)(v + (size_t)node * 128 + c * 8);
    float vr[8];
    #pragma unroll
    for (int k = 0; k < 8; ++k) vr[k] = bf2f(vv[k]);
    float4 wa = *(const float4*)(&W4[c * 8]);
    float4 wb = *(const float4*)(&W4[c * 8 + 4]);
    float b4v = b4[0];
    int p = beg;
    for (; p + 8 <= end; p += 8) {
        int2 se0 = csr_se[p];     int2 se1 = csr_se[p + 1];
        int2 se2 = csr_se[p + 2]; int2 se3 = csr_se[p + 3];
        int2 se4 = csr_se[p + 4]; int2 se5 = csr_se[p + 5];
        int2 se6 = csr_se[p + 6]; int2 se7 = csr_se[p + 7];
        us8 u0 = *(const us8*)(u + (size_t)se0.x * 128 + c * 8);
        us8 u1 = *(const us8*)(u + (size_t)se1.x * 128 + c * 8);
        us8 u2 = *(const us8*)(u + (size_t)se2.x * 128 + c * 8);
        us8 u3 = *(const us8*)(u + (size_t)se3.x * 128 + c * 8);
        us8 u4 = *(const us8*)(u + (size_t)se4.x * 128 + c * 8);
        us8 u5 = *(const us8*)(u + (size_t)se5.x * 128 + c * 8);
        us8 u6 = *(const us8*)(u + (size_t)se6.x * 128 + c * 8);
        us8 u7 = *(const us8*)(u + (size_t)se7.x * 128 + c * 8);
        float p0 = edot8(u0, vr, wa, wb);
        float p1 = edot8(u1, vr, wa, wb);
        float p2 = edot8(u2, vr, wa, wb);
        float p3 = edot8(u3, vr, wa, wb);
        float p4 = edot8(u4, vr, wa, wb);
        float p5 = edot8(u5, vr, wa, wb);
        float p6 = edot8(u6, vr, wa, wb);
        float p7 = edot8(u7, vr, wa, wb);
        if (c == 0) {
            out[se0.y] = 1.f / (1.f + expf(-(p0 + b4v)));
            out[se1.y] = 1.f / (1.f + expf(-(p1 + b4v)));
            out[se2.y] = 1.f / (1.f + expf(-(p2 + b4v)));
            out[se3.y] = 1.f / (1.f + expf(-(p3 + b4v)));
            out[se4.y] = 1.f / (1.f + expf(-(p4 + b4v)));
            out[se5.y] = 1.f / (1.f + expf(-(p5 + b4v)));
            out[se6.y] = 1.f / (1.f + expf(-(p6 + b4v)));
            out[se7.y] = 1.f / (1.f + expf(-(p7 + b4v)));
        }
    }
    for (; p + 4 <= end; p += 4) {
        int2 se0 = csr_se[p];     int2 se1 = csr_se[p + 1];
        int2 se2 = csr_se[p + 2]; int2 se3 = csr_se[p + 3];
        us8 u0 = *(const us8*)(u + (size_t)se0.x * 128 + c * 8);
        us8 u1 = *(const us8*)(u + (size_t)se1.x * 128 + c * 8);
        us8 u2 = *(const us8*)(u + (size_t)se2.x * 128 + c * 8);
        us8 u3 = *(const us8*)(u + (size_t)se3.x * 128 + c * 8);
        float p0 = edot8(u0, vr, wa, wb);
        float p1 = edot8(u1, vr, wa, wb);
        float p2 = edot8(u2, vr, wa, wb);
        float p3 = edot8(u3, vr, wa, wb);
        if (c == 0) {
            out[se0.y] = 1.f / (1.f + expf(-(p0 + b4v)));
            out[se1.y] = 1.f / (1.f + expf(-(p1 + b4v)));
            out[se2.y] = 1.f / (1.f + expf(-(p2 + b4v)));
            out[se3.y] = 1.f / (1.f + expf(-(p3 + b4v)));
        }
    }
    for (; p < end; ++p) {
        int2 se = csr_se[p];
        us8 uu = *(const us8*)(u + (size_t)se.x * 128 + c * 8);
        float ps = edot8(uu, vr, wa, wb);
        if (c == 0)
            out[se.y] = 1.f / (1.f + expf(-(ps + b4v)));
    }
}

// ---------------- launcher ----------------

extern "C" void kernel_launch(void* const* d_in, const int* in_sizes, int n_in,
                              void* d_out, int out_size, void* d_ws, size_t ws_size,
                              hipStream_t stream) {
    const float* x  = (const float*)d_in[0];
    const int*   ei = (const int*)d_in[1];
    const float* W1 = (const float*)d_in[2];
    const float* b1 = (const float*)d_in[3];
    const float* W2 = (const float*)d_in[4];
    const float* b2 = (const float*)d_in[5];
    const float* W3 = (const float*)d_in[6];
    const float* b3 = (const float*)d_in[7];
    const float* W4 = (const float*)d_in[8];
    const float* b4 = (const float*)d_in[9];

    int N = in_sizes[0] / 256;      // 50000
    int E = in_sizes[1] / 2;        // 1.6M

    char* ws = (char*)d_ws;
    size_t off = 0;
    auto alloc = [&](size_t bytes) -> void* {
        void* p = ws + off;
        off += (bytes + 255) & ~(size_t)255;
        return p;
    };
    int*      flag    = (int*)     alloc(256);
    int*      srcn    = (int*)     alloc((size_t)E * 4);
    int*      dstn    = (int*)     alloc((size_t)E * 4);
    int*      deg     = (int*)     alloc((size_t)N * 4);
    int*      offs    = (int*)     alloc((size_t)(N + 1) * 4);
    int*      cursor  = (int*)     alloc((size_t)N * 4);
    int*      excl    = (int*)     alloc((size_t)N * 4);
    int*      bsum    = (int*)     alloc(1024);
    float*    dinv    = (float*)   alloc((size_t)N * 4);
    int2*     csr_se  = (int2*)    alloc((size_t)E * 8);
    ushort_t* gbuf    = (ushort_t*)alloc((size_t)(N + 1) * 128 * 2); // + zero row
    ushort_t* ubuf    = (ushort_t*)alloc((size_t)N * 128 * 2);       // bf16 u table
    ushort_t* vbuf    = (ushort_t*)alloc((size_t)N * 128 * 2);       // bf16 v table
    ushort_t* hbuf    = (ushort_t*)alloc((size_t)N * 128 * 2);       // bf16 h
    ushort_t* Wt1     = (ushort_t*)alloc(128 * 256 * 2);
    ushort_t* Wt2     = (ushort_t*)alloc(128 * 128 * 2);
    ushort_t* Wt3a    = (ushort_t*)alloc(128 * 128 * 2);
    ushort_t* Wt3b    = (ushort_t*)alloc(128 * 128 * 2);
    (void)ws_size; (void)n_in; (void)out_size;

    float* outp = (float*)d_out;
    int gE = (E + 255) / 256;
    int gN4 = (N + 3) / 4;
    int nb = (N + 255) / 256;       // scan blocks (196 <= 256)
    int RB = (N + 7) / 8;           // dst-range per XCD

    // dtype hedge + index normalization
    int nwords = (2 * E < 4096) ? 2 * E : 4096;
    detect_i64<<<1, 1024, 0, stream>>>(ei, nwords, flag);
    normalize_idx<<<gE, 256, 0, stream>>>(ei, E, flag, srcn, dstn);
    conv_weights<<<320, 256, 0, stream>>>(W1, W2, W3, Wt1, Wt2, Wt3a, Wt3b);

    // CSR (by dst) + dinv, XCD dst-range partitioned; zero the padding row of gbuf
    zero_i32<<<(N + 255) / 256, 256, 0, stream>>>(deg, N);
    zero_i32<<<1, 256, 0, stream>>>((int*)(gbuf + (size_t)N * 128), 64);
    count_deg_part<<<gE * 8, 256, 0, stream>>>(dstn, deg, E, RB);
    scan_blk<<<nb, 256, 0, stream>>>(deg, excl, bsum, N);
    scan_top<<<1, 256, 0, stream>>>(bsum, nb);
    scan_fin<<<nb, 256, 0, stream>>>(deg, excl, bsum, offs, cursor, dinv, N, nb);
    fill_csr_part<<<gE * 8, 256, 0, stream>>>(srcn, dstn, cursor, csr_se, E, RB);

    int gM = (N + 63) / 64;
    // layer 1: g1 = bf16(dinv * (x @ W1));  h1 = bf16(relu(dinv*(sum g1) + b1))
    gemm_mfma<<<gM, 256, 0, stream>>>(x, Wt1, gbuf, dinv, nullptr, N, 256);
    pull_agg<<<gN4, 256, 0, stream>>>(gbuf, csr_se, offs, dinv, b1, hbuf, N, 1);
    // layer 2: g2 = bf16(dinv * (h1 @ W2)); h2 = bf16(dinv*(sum g2) + b2)
    gemm_regB<<<512, 256, 0, stream>>>(hbuf, Wt2, gbuf, dinv, nullptr, N);
    pull_agg<<<gN4, 256, 0, stream>>>(gbuf, csr_se, offs, dinv, b2, hbuf, N, 0);
    // factorized edge MLP: u = bf16(h2 @ W3a), v = bf16(h2 @ W3b + b3)
    gemm_regB<<<512, 256, 0, stream>>>(hbuf, Wt3a, ubuf, nullptr, nullptr, N);
    gemm_regB<<<512, 256, 0, stream>>>(hbuf, Wt3b, vbuf, nullptr, b3, N);
    // score per edge: dst-segment order, v in registers, 8-edge ILP
    edge_score_seg<<<(N + 15) / 16, 256, 0, stream>>>(ubuf, vbuf, csr_se, offs,
                                                      W4, b4, outp, N);
}